// Round 5
// baseline (8117.065 us; speedup 1.0000x reference)
//
#include <hip/hip_runtime.h>
#include <hip/hip_bf16.h>

typedef __hip_bfloat16 bf16;
typedef __attribute__((ext_vector_type(8))) short short8;
typedef __attribute__((ext_vector_type(4))) float f32x4;

#define MFMA(va, vb, vc) __builtin_amdgcn_mfma_f32_16x16x32_bf16(va, vb, vc, 0, 0, 0)

__device__ __forceinline__ float to_f(float x) { return x; }
__device__ __forceinline__ float to_f(bf16 x) { return __bfloat162float(x); }
__device__ __forceinline__ float ldp(const void* p, size_t i, bool f32) {
  return f32 ? ((const float*)p)[i] : __bfloat162float(((const bf16*)p)[i]);
}
__device__ __forceinline__ short f2b(float f) {
  bf16 h = __float2bfloat16(f);
  return *reinterpret_cast<short*>(&h);
}
__device__ __forceinline__ float b2f(short s_) {
  unsigned int ui = ((unsigned int)(unsigned short)s_) << 16;
  float f;
  __builtin_memcpy(&f, &ui, 4);
  return f;
}
// gate-interleave permutation: source col c = g*256+i (g<3,i<256) ->
// col' = 64*(i>>4) + 16*g + (i&15). MFMA n-tile == gate in fused cells.
__device__ __forceinline__ int perm1024(int c) {
  return ((c & 255) >> 4) * 64 + (c >> 8) * 16 + (c & 15);
}

// dtype probe: f32 data read as u16 pairs shows implausible bf16 exponents.
__global__ void detect_kernel(const void* __restrict__ probe,
                              unsigned* __restrict__ flag) {
  __shared__ int sbad;
  if (threadIdx.x == 0) sbad = 0;
  __syncthreads();
  const unsigned short* u = (const unsigned short*)probe;
  int bad = 0;
  for (int i = threadIdx.x; i < 2048; i += 256) {
    unsigned short w = u[i];
    unsigned e = (w >> 7) & 0xFFu;
    bool plaus = (w == 0) || (w == 0x8000u) || (e >= 0x60u && e <= 0x7Eu);
    if (!plaus) bad++;
  }
  atomicAdd(&sbad, bad);
  __syncthreads();
  if (threadIdx.x == 0) *flag = (sbad > 100) ? 1u : 0u;
}

// ---- weight prep: params (f32|bf16) -> bf16 ws ----
// transp: 0=copy, 1=transpose, 2=transpose+perm1024, 3=copy+perm1024
#define MAXSEG 24
struct PrepArgs {
  int nseg;
  const void* src[MAXSEG];
  long long soff[MAXSEG];
  short* dst[MAXSEG];
  int scols[MAXSEG];
  int dstride[MAXSEG];
  int transp[MAXSEG];
  long long prefix[MAXSEG + 1];
};
__global__ void prep_kernel(PrepArgs a, const unsigned* __restrict__ dflag) {
  const bool isf32 = (*dflag != 0u);
  long long i = (long long)blockIdx.x * 256 + threadIdx.x;
  if (i >= a.prefix[a.nseg]) return;
  int s = 0;
  while (i >= a.prefix[s + 1]) s++;
  long long loc = i - a.prefix[s];
  long long r = loc / a.scols[s], c = loc % a.scols[s];
  float v = a.src[s] ? ldp(a.src[s], (size_t)(a.soff[s] + loc), isf32) : 0.f;
  int tp = a.transp[s];
  long long idx;
  if (tp == 1)
    idx = c * a.dstride[s] + r;
  else if (tp == 2)
    idx = (long long)perm1024((int)c) * a.dstride[s] + r;
  else if (tp == 3)
    idx = perm1024((int)c);
  else
    idx = r * a.dstride[s] + c;
  a.dst[s][idx] = f2b(v);
}

// ---- multi-job GEMM with LDS staging (token tables only now) ----
struct GJob {
  const bf16* A;
  const short* WT;
  const bf16* bias;
  float* Cf;
  bf16* Ch;
  int lda, wst, K, M, N, flags;  // flags: 4=tanh
};
struct GJobs {
  GJob j[4];
};

__global__ __launch_bounds__(256) void mj_gemm(GJobs args) {
  GJob jb = args.j[blockIdx.z];
  const int n0 = blockIdx.x * 128, m0 = blockIdx.y * 128;
  if (n0 >= jb.N || m0 >= jb.M) return;
  __shared__ short As[128][40];
  __shared__ short Bs[128][40];
  const int tid = threadIdx.x, lane = tid & 63, wave = tid >> 6;
  const int srow = tid >> 1, skoff = (tid & 1) * 16;
  const int wr = (wave >> 1) * 64, wc = (wave & 1) * 64;

  const short* abase =
      (const short*)jb.A + (long long)(m0 + srow) * jb.lda + skoff;
  const short* bbase = jb.WT + (long long)(n0 + srow) * jb.wst + skoff;
  f32x4 acc[4][4];
#pragma unroll
  for (int i = 0; i < 4; i++)
#pragma unroll
    for (int j = 0; j < 4; j++) acc[i][j] = 0.f;

  short8 a0 = *(const short8*)(abase);
  short8 a1 = *(const short8*)(abase + 8);
  short8 b0 = *(const short8*)(bbase);
  short8 b1 = *(const short8*)(bbase + 8);
  for (int k0 = 0; k0 < jb.K; k0 += 32) {
    __syncthreads();
    *(short8*)&As[srow][skoff] = a0;
    *(short8*)&As[srow][skoff + 8] = a1;
    *(short8*)&Bs[srow][skoff] = b0;
    *(short8*)&Bs[srow][skoff + 8] = b1;
    __syncthreads();
    int kn = (k0 + 32 < jb.K) ? k0 + 32 : k0;
    a0 = *(const short8*)(abase + kn);
    a1 = *(const short8*)(abase + kn + 8);
    b0 = *(const short8*)(bbase + kn);
    b1 = *(const short8*)(bbase + kn + 8);
    short8 af[4], bfr[4];
#pragma unroll
    for (int i = 0; i < 4; i++)
      af[i] = *(short8*)&As[wr + i * 16 + (lane & 15)][(lane >> 4) * 8];
#pragma unroll
    for (int j = 0; j < 4; j++)
      bfr[j] = *(short8*)&Bs[wc + j * 16 + (lane & 15)][(lane >> 4) * 8];
#pragma unroll
    for (int i = 0; i < 4; i++)
#pragma unroll
      for (int j = 0; j < 4; j++) acc[i][j] = MFMA(af[i], bfr[j], acc[i][j]);
  }
  const int N = jb.N;
#pragma unroll
  for (int j = 0; j < 4; j++) {
    int col = n0 + wc + j * 16 + (lane & 15);
    float bv = jb.bias ? to_f(jb.bias[col]) : 0.f;
#pragma unroll
    for (int i = 0; i < 4; i++) {
#pragma unroll
      for (int r = 0; r < 4; r++) {
        int row = m0 + wr + i * 16 + (lane >> 4) * 4 + r;
        float v = acc[i][j][r] + bv;
        if (jb.flags & 4) v = tanhf(v);
        if (jb.Cf) jb.Cf[(long long)row * N + col] = v;
        if (jb.Ch) jb.Ch[(long long)row * N + col] = __float2bfloat16(v);
      }
    }
  }
}

// ---- the whole network, one block = 8 batch rows, ZERO grid syncs ----
struct NetArgs {
  const short* WTf;   // enc Whh_f^T perm [1024][256]
  const short* WTb;   // enc Whh_b^T perm [1024][256]
  const bf16* biasf;  // perm bhh_f [1024]
  const bf16* biasb;  // perm bhh_b [1024]
  const int* src;
  const bf16* giTabF;
  const bf16* giTabB;
  const bf16* giTabE;
  const short* WT5;  // [256][512]
  const bf16* B5;
  const short* WT6;  // [256][512]
  const bf16* B6;
  const short* WcT;  // [1024][256]
  const bf16* Bc;
  const short* W7bT;  // [1024][512] perm
  const short* W8bT;  // [128][768]
  const float* fcTab;  // [128][128]
  const void* v;
  const unsigned* dflag;
  const int* trg;
  bf16* bse;   // [2048*24][512]  (flat row = b*24+s)
  bf16* proj;  // [2048*24][256]
  float* out;
};

__device__ __forceinline__ void wc_gemm(const short (*hdbf)[264],
                                        short (*ghw)[1032], const short* WcT,
                                        const bf16* Bc, int wave, int u,
                                        int kq) {
  short8 af[8];
#pragma unroll
  for (int kt = 0; kt < 8; kt++)
    af[kt] = *(const short8*)&hdbf[u][kt * 32 + kq * 8];
  for (int nt = 0; nt < 16; nt++) {
    const int n = wave * 256 + nt * 16 + u;
    const short* bp = WcT + (size_t)n * 256 + kq * 8;
    f32x4 acc = {0.f, 0.f, 0.f, 0.f};
#pragma unroll
    for (int kt = 0; kt < 8; kt++)
      acc = MFMA(af[kt], *(const short8*)(bp + kt * 32), acc);
    const float bv = to_f(Bc[n]);
#pragma unroll
    for (int r = 0; r < 4; r++) {
      const int row = kq * 4 + r;
      if (row < 8) ghw[row][n] = f2b(acc[r] + bv);
    }
  }
}

__global__ __launch_bounds__(256, 1) void net_persist(NetArgs a) {
  const int bid = blockIdx.x;        // 0..255
  const int r0 = bid * 8;            // batch rows [r0, r0+8)
  const int tid = threadIdx.x, lane = tid & 63, wave = tid >> 6;
  const int u = lane & 15, kq = lane >> 4;

  __shared__ short hbf[2][2][16][264];  // [buf][dir][row16][k], rows 8-15 = 0
  __shared__ float hF[2][8][260];       // f32 enc h state
  __shared__ short xr[16][776];         // dec [w(0:512)|hn(512:768)]
  __shared__ short ghw[8][1032];        // [gh(0:768)|hWh(768:1024)]
  __shared__ short hdbf[16][264];
  __shared__ float hdF[8][260];
  __shared__ float esc[8][24];
  __shared__ float aw[8][24];

  for (int i = tid; i < 2 * 2 * 16 * 264; i += 256) (&hbf[0][0][0][0])[i] = 0;
  for (int i = tid; i < 2 * 8 * 260; i += 256) (&hF[0][0][0])[i] = 0.f;
  for (int i = tid; i < 8 * 776; i += 256) xr[8 + i / 776][i % 776] = 0;
  for (int i = tid; i < 8 * 264; i += 256) hdbf[8 + i / 264][i % 264] = 0;
  __syncthreads();

  // ================= encoder: 24 steps, both directions =================
  for (int s = 0; s < 24; s++) {
    const int cur = s & 1, nxt = cur ^ 1;
    for (int dir = 0; dir < 2; dir++) {
      const int pos = dir ? (23 - s) : s;
      const short* WT = dir ? a.WTb : a.WTf;
      const bf16* bias = dir ? a.biasb : a.biasf;
      const bf16* giT = dir ? a.giTabB : a.giTabF;
      const int* srcp = a.src + (size_t)pos * 2048 + r0;
      short8 af[8];
#pragma unroll
      for (int kt = 0; kt < 8; kt++)
        af[kt] = *(const short8*)&hbf[cur][dir][u][kt * 32 + kq * 8];
#pragma unroll
      for (int gb = 0; gb < 4; gb++) {
        const int grp = wave * 4 + gb;
        f32x4 g0 = {0.f, 0.f, 0.f, 0.f}, g1 = g0, g2 = g0;
        const short* bp = WT + (size_t)(grp * 64 + u) * 256 + kq * 8;
#pragma unroll
        for (int kt = 0; kt < 8; kt++) {
          g0 = MFMA(af[kt], *(const short8*)(bp + kt * 32), g0);
          g1 = MFMA(af[kt], *(const short8*)(bp + 16 * 256 + kt * 32), g1);
          g2 = MFMA(af[kt], *(const short8*)(bp + 32 * 256 + kt * 32), g2);
        }
        const int i_h = grp * 16 + u;
        const float b0 = to_f(bias[grp * 64 + u]);
        const float b1 = to_f(bias[grp * 64 + 16 + u]);
        const float b2 = to_f(bias[grp * 64 + 32 + u]);
#pragma unroll
        for (int r = 0; r < 4; r++) {
          const int row = kq * 4 + r;
          if (row < 8) {
            const int tok = srcp[row];
            const bf16* gp = giT + (size_t)tok * 768 + i_h;
            float ir = to_f(gp[0]), iz = to_f(gp[256]), in_ = to_f(gp[512]);
            float hr = g0[r] + b0, hz = g1[r] + b1, hn = g2[r] + b2;
            float hv = hF[dir][row][i_h];
            float rr = 1.f / (1.f + expf(-(ir + hr)));
            float zz = 1.f / (1.f + expf(-(iz + hz)));
            float nn = tanhf(in_ + rr * hn);
            float o = (1.f - zz) * nn + zz * hv;
            hF[dir][row][i_h] = o;
            hbf[nxt][dir][row][i_h] = f2b(o);
            a.bse[(size_t)(r0 + row) * 12288 + (size_t)pos * 512 + dir * 256 +
                  i_h] = __float2bfloat16(o);
          }
        }
      }
    }
    __syncthreads();
  }

  // ====== mid: hidden = tanh([hf|hb]@WT5^T+B5); proj = bse@WT6^T+B6 ======
  {
    short8 af[16];
#pragma unroll
    for (int kt = 0; kt < 8; kt++) {
      af[kt] = *(const short8*)&hbf[0][0][u][kt * 32 + kq * 8];
      af[kt + 8] = *(const short8*)&hbf[0][1][u][kt * 32 + kq * 8];
    }
    for (int nt = 0; nt < 4; nt++) {
      const int n = wave * 64 + nt * 16 + u;
      const short* bp = a.WT5 + (size_t)n * 512 + kq * 8;
      f32x4 acc = {0.f, 0.f, 0.f, 0.f};
#pragma unroll
      for (int kt = 0; kt < 16; kt++)
        acc = MFMA(af[kt], *(const short8*)(bp + kt * 32), acc);
      const float bv = to_f(a.B5[n]);
#pragma unroll
      for (int r = 0; r < 4; r++) {
        const int row = kq * 4 + r;
        if (row < 8) {
          float v_ = tanhf(acc[r] + bv);
          hdF[row][n] = v_;
          hdbf[row][n] = f2b(v_);
        }
      }
    }
  }
  for (int mt = wave; mt < 12; mt += 4) {  // proj: M=192 own rows
    short8 af[16];
    const short* Ab =
        (const short*)a.bse + ((size_t)r0 * 24 + mt * 16 + u) * 512 + kq * 8;
#pragma unroll
    for (int kt = 0; kt < 16; kt++) af[kt] = *(const short8*)(Ab + kt * 32);
    for (int nt = 0; nt < 16; nt++) {
      const int n = nt * 16 + u;
      const short* bp = a.WT6 + (size_t)n * 512 + kq * 8;
      f32x4 acc = {0.f, 0.f, 0.f, 0.f};
#pragma unroll
      for (int kt = 0; kt < 16; kt++)
        acc = MFMA(af[kt], *(const short8*)(bp + kt * 32), acc);
      const float bv = to_f(a.B6[n]);
#pragma unroll
      for (int r = 0; r < 4; r++) {
        const int m = mt * 16 + kq * 4 + r;
        a.proj[((size_t)r0 * 24 + m) * 256 + n] =
            __float2bfloat16(acc[r] + bv);
      }
    }
  }
  __syncthreads();

  // ============================ decoder ============================
  wc_gemm(hdbf, ghw, a.WcT, a.Bc, wave, u, kq);
  __syncthreads();
  const bool isf32 = (*a.dflag != 0u);
  float vv4[4];
#pragma unroll
  for (int c = 0; c < 4; c++) vv4[c] = ldp(a.v, lane + c * 64, isf32);

  for (int t = 0; t < 24; t++) {
    const int* trg_t = a.trg + (size_t)t * 2048 + r0;
    // --- attention energies: wave handles rows 2w, 2w+1 ---
    for (int rr_ = 0; rr_ < 2; rr_++) {
      const int row = wave * 2 + rr_;
      const short* prow =
          (const short*)a.proj + ((size_t)(r0 + row) * 24) * 256;
      float hw[4];
#pragma unroll
      for (int c = 0; c < 4; c++) hw[c] = b2f(ghw[row][768 + lane + c * 64]);
      for (int s = 0; s < 24; s++) {
        float tt = 0.f;
#pragma unroll
        for (int c = 0; c < 4; c++)
          tt += vv4[c] * tanhf(hw[c] + b2f(prow[s * 256 + lane + c * 64]));
#pragma unroll
        for (int off = 32; off > 0; off >>= 1) tt += __shfl_down(tt, off, 64);
        if (lane == 0) esc[row][s] = tt;
      }
    }
    __syncthreads();
    if (tid < 8) {
      float mx = -1e30f;
      for (int s = 0; s < 24; s++) mx = fmaxf(mx, esc[tid][s]);
      float sm = 0.f;
      for (int s = 0; s < 24; s++) {
        float e = expf(esc[tid][s] - mx);
        aw[tid][s] = e;
        sm += e;
      }
      float inv = 1.f / sm;
      for (int s = 0; s < 24; s++) aw[tid][s] *= inv;
    }
    __syncthreads();
    // --- weighted sum -> xr[:,0:512] ---
    for (int rr_ = 0; rr_ < 2; rr_++) {
      const int row = wave * 2 + rr_;
      const short* brow = (const short*)a.bse + (size_t)(r0 + row) * 12288;
      float wv[8];
#pragma unroll
      for (int d = 0; d < 8; d++) wv[d] = 0.f;
      for (int s = 0; s < 24; s++) {
        const float aa = aw[row][s];
#pragma unroll
        for (int d = 0; d < 8; d++)
          wv[d] += aa * b2f(brow[s * 512 + lane + d * 64]);
      }
#pragma unroll
      for (int d = 0; d < 8; d++) xr[row][lane + d * 64] = f2b(wv[d]);
    }
    __syncthreads();
    // --- cell GEMM: gi_dyn = w@W7bT^T (K=512, N=1024 perm) + GRU cell ---
    {
      short8 af[16];
#pragma unroll
      for (int kt = 0; kt < 16; kt++)
        af[kt] = *(const short8*)&xr[u][kt * 32 + kq * 8];
#pragma unroll
      for (int gb = 0; gb < 4; gb++) {
        const int grp = wave * 4 + gb;
        f32x4 g0 = {0.f, 0.f, 0.f, 0.f}, g1 = g0, g2 = g0;
        const short* bp = a.W7bT + (size_t)(grp * 64 + u) * 512 + kq * 8;
#pragma unroll
        for (int kt = 0; kt < 16; kt++) {
          g0 = MFMA(af[kt], *(const short8*)(bp + kt * 32), g0);
          g1 = MFMA(af[kt], *(const short8*)(bp + 16 * 512 + kt * 32), g1);
          g2 = MFMA(af[kt], *(const short8*)(bp + 32 * 512 + kt * 32), g2);
        }
        const int i_h = grp * 16 + u;
#pragma unroll
        for (int r = 0; r < 4; r++) {
          const int row = kq * 4 + r;
          if (row < 8) {
            const int tok = trg_t[row];
            const bf16* gp = a.giTabE + (size_t)tok * 768 + i_h;
            float ir = g0[r] + to_f(gp[0]);
            float iz = g1[r] + to_f(gp[256]);
            float in_ = g2[r] + to_f(gp[512]);
            float hr = b2f(ghw[row][i_h]);
            float hz = b2f(ghw[row][256 + i_h]);
            float hn = b2f(ghw[row][512 + i_h]);
            float hv = hdF[row][i_h];
            float rr2 = 1.f / (1.f + expf(-(ir + hr)));
            float zz = 1.f / (1.f + expf(-(iz + hz)));
            float nn = tanhf(in_ + rr2 * hn);
            float o = (1.f - zz) * nn + zz * hv;
            hdF[row][i_h] = o;
            short ob = f2b(o);
            hdbf[row][i_h] = ob;
            xr[row][512 + i_h] = ob;
          }
        }
      }
    }
    __syncthreads();
    // --- next-step ghw; then logits (disjoint, no sync needed between) ---
    wc_gemm(hdbf, ghw, a.WcT, a.Bc, wave, u, kq);
    {
      f32x4 accL[2] = {{0.f, 0.f, 0.f, 0.f}, {0.f, 0.f, 0.f, 0.f}};
#pragma unroll
      for (int kc = 0; kc < 3; kc++) {
        short8 af[8];
#pragma unroll
        for (int kt = 0; kt < 8; kt++)
          af[kt] = *(const short8*)&xr[u][kc * 256 + kt * 32 + kq * 8];
#pragma unroll
        for (int nt = 0; nt < 2; nt++) {
          const short* bp = a.W8bT +
                            (size_t)(wave * 32 + nt * 16 + u) * 768 +
                            kc * 256 + kq * 8;
#pragma unroll
          for (int kt = 0; kt < 8; kt++)
            accL[nt] = MFMA(af[kt], *(const short8*)(bp + kt * 32), accL[nt]);
        }
      }
#pragma unroll
      for (int nt = 0; nt < 2; nt++) {
        const int col = wave * 32 + nt * 16 + u;
#pragma unroll
        for (int r = 0; r < 4; r++) {
          const int row = kq * 4 + r;
          if (row < 8) {
            const int tok = trg_t[row];
            a.out[(size_t)(t + 1) * 2048 * 128 + (size_t)(r0 + row) * 128 +
                  col] = accL[nt][r] + a.fcTab[tok * 128 + col];
          }
        }
      }
    }
    __syncthreads();
  }
}

__global__ void sentinel_kernel(float* out, int n) {
  int i = blockIdx.x * 256 + threadIdx.x;
  if (i < n) out[i] = 123.0f;
}

extern "C" void kernel_launch(void* const* d_in, const int* in_sizes, int n_in,
                              void* d_out, int out_size, void* d_ws,
                              size_t ws_size, hipStream_t stream) {
  const int B = 2048, S = 24, VOUT = 128;
  const int* src = (const int*)d_in[0];
  const int* trg = (const int*)d_in[1];
  const void* enc_emb = d_in[2];
  const void* enc_Wih_f = d_in[3];
  const void* enc_Whh_f = d_in[4];
  const void* enc_bih_f = d_in[5];
  const void* enc_bhh_f = d_in[6];
  const void* enc_Wih_b = d_in[7];
  const void* enc_Whh_b = d_in[8];
  const void* enc_bih_b = d_in[9];
  const void* enc_bhh_b = d_in[10];
  const void* enc_fcW = d_in[11];
  const void* enc_fcb = d_in[12];
  const void* attn_Wh = d_in[13];
  const void* attn_We = d_in[14];
  const void* attn_b = d_in[15];
  const void* attn_v = d_in[16];
  const void* dec_emb = d_in[17];
  const void* dec_Wih = d_in[18];
  const void* dec_Whh = d_in[19];
  const void* dec_bih = d_in[20];
  const void* dec_bhh = d_in[21];
  const void* fcW = d_in[22];
  const void* fcb = d_in[23];
  float* out = (float*)d_out;

  // ---- workspace layout ----
  size_t need = 0;
  auto place = [&](size_t bytes) {
    size_t off = need;
    need += (bytes + 255) & ~(size_t)255;
    return off;
  };
  size_t o_flag = place(256);
  size_t o_wstart = need;  // memset-0 region start
  size_t oEmbE = place(64 * 320 * 2);    // enc_emb bf16, k-pad 320
  size_t oEmbD = place(128 * 320 * 2);   // dec_emb bf16
  size_t oWT1 = place(768 * 320 * 2);    // enc_Wih_f^T [768][320]
  size_t oWT2 = place(1024 * 256 * 2);   // enc_Whh_f^T perm1024
  size_t oWT3 = place(768 * 320 * 2);    // enc_Wih_b^T
  size_t oWT4 = place(1024 * 256 * 2);   // enc_Whh_b^T perm1024
  size_t oWT5 = place(256 * 512 * 2);    // enc_fcW^T
  size_t oWT6 = place(256 * 512 * 2);    // attn_We^T
  size_t oWcT = place(1024 * 256 * 2);   // [dec_Whh | attn_Wh]^T
  size_t oW7aT = place(768 * 320 * 2);   // dec_Wih[0:300]^T [768][320]
  size_t oW7bT = place(1024 * 512 * 2);  // dec_Wih[300:812]^T perm1024
  size_t oW8aT = place(128 * 320 * 2);   // fcW[768:1068]^T (emb) [128][320]
  size_t oW8bT = place(128 * 768 * 2);   // fcW k-perm [weighted|hn]
  size_t oB1 = place(768 * 2), oB2 = place(1024 * 2);
  size_t oB3 = place(768 * 2), oB4 = place(1024 * 2);
  size_t oB5 = place(256 * 2), oB6 = place(256 * 2);
  size_t oB7 = place(768 * 2), oBc = place(1024 * 2), oB8 = place(128 * 2);
  size_t o_wend = need;
  size_t o_bse = place((size_t)B * S * 512 * 2);
  size_t o_proj = place((size_t)B * S * 256 * 2);
  size_t o_gtF = place(128 * 768 * 2);  // giTab fwd (64 used, pad 128)
  size_t o_gtB = place(128 * 768 * 2);
  size_t o_gtE = place(128 * 768 * 2);
  size_t o_fcT = place(128 * 128 * 4);  // f32 fc emb table

  if (ws_size < need) {
    sentinel_kernel<<<(out_size + 255) / 256, 256, 0, stream>>>(out, out_size);
    return;
  }

  char* base = (char*)d_ws;
  unsigned* dflag = (unsigned*)(base + o_flag);
  bf16* embE = (bf16*)(base + oEmbE);
  bf16* embD = (bf16*)(base + oEmbD);
  short* WT1 = (short*)(base + oWT1);
  short* WT2p = (short*)(base + oWT2);
  short* WT3 = (short*)(base + oWT3);
  short* WT4p = (short*)(base + oWT4);
  short* WT5 = (short*)(base + oWT5);
  short* WT6 = (short*)(base + oWT6);
  short* WcT = (short*)(base + oWcT);
  short* W7aT = (short*)(base + oW7aT);
  short* W7bTp = (short*)(base + oW7bT);
  short* W8aT = (short*)(base + oW8aT);
  short* W8bT = (short*)(base + oW8bT);
  bf16 *B1 = (bf16*)(base + oB1), *B2p = (bf16*)(base + oB2);
  bf16 *B3 = (bf16*)(base + oB3), *B4p = (bf16*)(base + oB4);
  bf16 *B5 = (bf16*)(base + oB5), *B6 = (bf16*)(base + oB6);
  bf16 *B7 = (bf16*)(base + oB7), *Bc = (bf16*)(base + oBc);
  bf16* B8 = (bf16*)(base + oB8);
  bf16* bse = (bf16*)(base + o_bse);
  bf16* proj = (bf16*)(base + o_proj);
  bf16* giTabF = (bf16*)(base + o_gtF);
  bf16* giTabB = (bf16*)(base + o_gtB);
  bf16* giTabE = (bf16*)(base + o_gtE);
  float* fcTab = (float*)(base + o_fcT);

  detect_kernel<<<1, 256, 0, stream>>>(enc_emb, dflag);
  (void)hipMemsetAsync(base + o_wstart, 0, o_wend - o_wstart, stream);

  // ---- weight prep ----
  PrepArgs pa;
  int ns = 0;
  long long tot = 0;
  auto seg = [&](const void* s, long long soff, short* dst, int scols,
                 int dstride, int transp, long long count) {
    pa.src[ns] = s;
    pa.soff[ns] = soff;
    pa.dst[ns] = dst;
    pa.scols[ns] = scols;
    pa.dstride[ns] = dstride;
    pa.transp[ns] = transp;
    pa.prefix[ns] = tot;
    tot += count;
    ns++;
  };
  seg(enc_emb, 0, (short*)embE, 300, 320, 0, 64 * 300);
  seg(dec_emb, 0, (short*)embD, 300, 320, 0, 128 * 300);
  seg(enc_Wih_f, 0, WT1, 768, 320, 1, 230400);
  seg(enc_Whh_f, 0, WT2p, 768, 256, 2, 196608);
  seg(enc_Wih_b, 0, WT3, 768, 320, 1, 230400);
  seg(enc_Whh_b, 0, WT4p, 768, 256, 2, 196608);
  seg(enc_fcW, 0, WT5, 256, 512, 1, 131072);
  seg(attn_We, 0, WT6, 256, 512, 1, 131072);
  seg(dec_Whh, 0, WcT, 768, 256, 1, 196608);
  seg(attn_Wh, 0, WcT + 768 * 256, 256, 256, 1, 65536);
  seg(dec_Wih, 0, W7aT, 768, 320, 1, 300 * 768);                      // 0:300
  seg(dec_Wih, (long long)300 * 768, W7bTp, 768, 512, 2, 512 * 768);  // rest
  seg(fcW, (long long)768 * 128, W8aT, 128, 320, 1, 300 * 128);  // emb part
  seg(fcW, (long long)256 * 128, W8bT, 128, 768, 1, 512 * 128);  // weighted
  seg(fcW, 0, W8bT + 512, 128, 768, 1, 256 * 128);               // hn
  seg(enc_bih_f, 0, (short*)B1, 768, 768, 0, 768);
  seg(enc_bhh_f, 0, (short*)B2p, 768, 1024, 3, 768);
  seg(enc_bih_b, 0, (short*)B3, 768, 768, 0, 768);
  seg(enc_bhh_b, 0, (short*)B4p, 768, 1024, 3, 768);
  seg(enc_fcb, 0, (short*)B5, 256, 256, 0, 256);
  seg(attn_b, 0, (short*)B6, 256, 256, 0, 256);
  seg(dec_bih, 0, (short*)B7, 768, 768, 0, 768);
  seg(dec_bhh, 0, (short*)Bc, 768, 768, 0, 768);  // Bc[768:1024] stays 0
  seg(fcb, 0, (short*)B8, 128, 128, 0, 128);
  pa.prefix[ns] = tot;
  pa.nseg = ns;
  prep_kernel<<<(int)((tot + 255) / 256), 256, 0, stream>>>(pa, dflag);

  (void)hipMemsetAsync(out, 0, (size_t)B * VOUT * 4, stream);  // outputs[0]=0

  // ---- token tables: VIN=64 / VOUT=128 distinct rows only ----
  {
    GJobs a{};
    a.j[0] = {embE, WT1, B1, nullptr, giTabF, 320, 320, 320, 128, 768, 0};
    a.j[1] = {embE, WT3, B3, nullptr, giTabB, 320, 320, 320, 128, 768, 0};
    a.j[2] = {embD, W7aT, B7, nullptr, giTabE, 320, 320, 320, 128, 768, 0};
    a.j[3] = {embD, W8aT, B8, fcTab, nullptr, 320, 320, 320, 128, 128, 0};
    mj_gemm<<<dim3(6, 1, 4), 256, 0, stream>>>(a);
  }

  // ---- the whole network: one kernel, 256 blocks x 8 rows, no barriers ----
  {
    NetArgs na{WT2p, WT4p, B2p, B4p, src,  giTabF, giTabB, giTabE,
               WT5,  B5,   WT6,  B6,  WcT, Bc,     W7bTp,  W8bT,
               fcTab, attn_v, dflag, trg, bse, proj, out};
    net_persist<<<256, 256, 0, stream>>>(na);
  }
}

// Round 6
// 5248.281 us; speedup vs baseline: 1.5466x; 1.5466x over previous
//
#include <hip/hip_runtime.h>
#include <hip/hip_bf16.h>

typedef __hip_bfloat16 bf16;
typedef __attribute__((ext_vector_type(8))) short short8;
typedef __attribute__((ext_vector_type(4))) float f32x4;

#define MFMA(va, vb, vc) \
  __builtin_amdgcn_mfma_f32_16x16x32_bf16(va, vb, vc, 0, 0, 0)

__device__ __forceinline__ float to_f(float x) { return x; }
__device__ __forceinline__ float to_f(bf16 x) { return __bfloat162float(x); }
__device__ __forceinline__ float ldp(const void* p, size_t i, bool f32) {
  return f32 ? ((const float*)p)[i] : __bfloat162float(((const bf16*)p)[i]);
}
__device__ __forceinline__ short f2b(float f) {
  bf16 h = __float2bfloat16(f);
  return *reinterpret_cast<short*>(&h);
}
__device__ __forceinline__ float b2f(short s_) {
  unsigned int ui = ((unsigned int)(unsigned short)s_) << 16;
  float f;
  __builtin_memcpy(&f, &ui, 4);
  return f;
}
// gate-interleave permutation: source col c = g*256+i (g<3,i<256) ->
// col' = 64*(i>>4) + 16*g + (i&15). MFMA n-tile == gate in fused cells.
__device__ __forceinline__ int perm1024(int c) {
  return ((c & 255) >> 4) * 64 + (c >> 8) * 16 + (c & 15);
}

// dtype probe: f32 data read as u16 pairs shows implausible bf16 exponents.
__global__ void detect_kernel(const void* __restrict__ probe,
                              unsigned* __restrict__ flag) {
  __shared__ int sbad;
  if (threadIdx.x == 0) sbad = 0;
  __syncthreads();
  const unsigned short* u = (const unsigned short*)probe;
  int bad = 0;
  for (int i = threadIdx.x; i < 2048; i += 256) {
    unsigned short w = u[i];
    unsigned e = (w >> 7) & 0xFFu;
    bool plaus = (w == 0) || (w == 0x8000u) || (e >= 0x60u && e <= 0x7Eu);
    if (!plaus) bad++;
  }
  atomicAdd(&sbad, bad);
  __syncthreads();
  if (threadIdx.x == 0) *flag = (sbad > 100) ? 1u : 0u;
}

// ---- weight prep: params (f32|bf16) -> bf16 ws ----
// transp: 0=copy, 1=transpose, 2=transpose+perm1024, 3=copy+perm1024
#define MAXSEG 24
struct PrepArgs {
  int nseg;
  const void* src[MAXSEG];
  long long soff[MAXSEG];
  short* dst[MAXSEG];
  int scols[MAXSEG];
  int dstride[MAXSEG];
  int transp[MAXSEG];
  long long prefix[MAXSEG + 1];
};
__global__ void prep_kernel(PrepArgs a, const unsigned* __restrict__ dflag) {
  const bool isf32 = (*dflag != 0u);
  long long i = (long long)blockIdx.x * 256 + threadIdx.x;
  if (i >= a.prefix[a.nseg]) return;
  int s = 0;
  while (i >= a.prefix[s + 1]) s++;
  long long loc = i - a.prefix[s];
  long long r = loc / a.scols[s], c = loc % a.scols[s];
  float v = a.src[s] ? ldp(a.src[s], (size_t)(a.soff[s] + loc), isf32) : 0.f;
  int tp = a.transp[s];
  long long idx;
  if (tp == 1)
    idx = c * a.dstride[s] + r;
  else if (tp == 2)
    idx = (long long)perm1024((int)c) * a.dstride[s] + r;
  else if (tp == 3)
    idx = perm1024((int)c);
  else
    idx = r * a.dstride[s] + c;
  a.dst[s][idx] = f2b(v);
}

// ---- multi-job GEMM with LDS staging (token tables only) ----
struct GJob {
  const bf16* A;
  const short* WT;
  const bf16* bias;
  float* Cf;
  bf16* Ch;
  int lda, wst, K, M, N, flags;
};
struct GJobs {
  GJob j[4];
};

__global__ __launch_bounds__(256) void mj_gemm(GJobs args) {
  GJob jb = args.j[blockIdx.z];
  const int n0 = blockIdx.x * 128, m0 = blockIdx.y * 128;
  if (n0 >= jb.N || m0 >= jb.M) return;
  __shared__ short As[128][40];
  __shared__ short Bs[128][40];
  const int tid = threadIdx.x, lane = tid & 63, wave = tid >> 6;
  const int srow = tid >> 1, skoff = (tid & 1) * 16;
  const int wr = (wave >> 1) * 64, wc = (wave & 1) * 64;

  const short* abase =
      (const short*)jb.A + (long long)(m0 + srow) * jb.lda + skoff;
  const short* bbase = jb.WT + (long long)(n0 + srow) * jb.wst + skoff;
  f32x4 acc[4][4];
#pragma unroll
  for (int i = 0; i < 4; i++)
#pragma unroll
    for (int j = 0; j < 4; j++) acc[i][j] = 0.f;

  short8 a0 = *(const short8*)(abase);
  short8 a1 = *(const short8*)(abase + 8);
  short8 b0 = *(const short8*)(bbase);
  short8 b1 = *(const short8*)(bbase + 8);
  for (int k0 = 0; k0 < jb.K; k0 += 32) {
    __syncthreads();
    *(short8*)&As[srow][skoff] = a0;
    *(short8*)&As[srow][skoff + 8] = a1;
    *(short8*)&Bs[srow][skoff] = b0;
    *(short8*)&Bs[srow][skoff + 8] = b1;
    __syncthreads();
    int kn = (k0 + 32 < jb.K) ? k0 + 32 : k0;
    a0 = *(const short8*)(abase + kn);
    a1 = *(const short8*)(abase + kn + 8);
    b0 = *(const short8*)(bbase + kn);
    b1 = *(const short8*)(bbase + kn + 8);
    short8 af[4], bfr[4];
#pragma unroll
    for (int i = 0; i < 4; i++)
      af[i] = *(short8*)&As[wr + i * 16 + (lane & 15)][(lane >> 4) * 8];
#pragma unroll
    for (int j = 0; j < 4; j++)
      bfr[j] = *(short8*)&Bs[wc + j * 16 + (lane & 15)][(lane >> 4) * 8];
#pragma unroll
    for (int i = 0; i < 4; i++)
#pragma unroll
      for (int j = 0; j < 4; j++) acc[i][j] = MFMA(af[i], bfr[j], acc[i][j]);
  }
  const int N = jb.N;
#pragma unroll
  for (int j = 0; j < 4; j++) {
    int col = n0 + wc + j * 16 + (lane & 15);
    float bv = jb.bias ? to_f(jb.bias[col]) : 0.f;
#pragma unroll
    for (int i = 0; i < 4; i++) {
#pragma unroll
      for (int r = 0; r < 4; r++) {
        int row = m0 + wr + i * 16 + (lane >> 4) * 4 + r;
        float v = acc[i][j][r] + bv;
        if (jb.flags & 4) v = tanhf(v);
        if (jb.Cf) jb.Cf[(long long)row * N + col] = v;
        if (jb.Ch) jb.Ch[(long long)row * N + col] = __float2bfloat16(v);
      }
    }
  }
}

// ---- the whole network. 1 block = 4 batch rows. bse LDS-resident,
// proj in 48 VGPRs/lane. Zero grid syncs, zero activation HBM re-reads. ----
struct NetArgs {
  const short* WTf;
  const short* WTb;
  const bf16* biasf;
  const bf16* biasb;
  const int* src;
  const bf16* giTabF;
  const bf16* giTabB;
  const bf16* giTabE;
  const short* WT5;
  const bf16* B5;
  const short* WT6;
  const bf16* B6;
  const short* WcT;
  const bf16* Bc;
  const short* W7bT;
  const short* W8bT;
  const float* fcTab;
  const void* v;
  const unsigned* dflag;
  const int* trg;
  float* out;
};

__global__ __launch_bounds__(256, 1) void net_persist(NetArgs a) {
  const int bid = blockIdx.x;  // 0..511
  const int r0 = bid * 4;      // batch rows [r0, r0+4)
  const int tid = threadIdx.x, lane = tid & 63, wave = tid >> 6;
  const int u = lane & 15, kq = lane >> 4;

  __shared__ short bseL[96 * 512];  // 98.3 KB, flat row f = s*4+row
  __shared__ char regB[25216] __attribute__((aligned(16)));  // union region
  __shared__ short xr[16][776];   // [w(0:512)|hn(512:768)], rows 4-15 zero
  __shared__ short ghw[4][1032];  // [gh(0:768)|hWh(768:1024)]
  __shared__ float hdF[4][260];
  __shared__ float esc[4][24];
  __shared__ float aw[4][24];

  auto hbf = (short(*)[16][264])regB;            // [2][16][264] enc h bf16
  auto hF = (float(*)[4][260])(regB + 16896);    // [2][4][260]  enc h f32
  auto scr = (short(*)[12][64][4])regB;          // proj scratch (aliases hbf)

  for (int i = tid; i < 25216 / 2; i += 256) ((short*)regB)[i] = 0;
  for (int i = tid; i < 16 * 776; i += 256) (&xr[0][0])[i] = 0;
  __syncthreads();

  // ================= encoder: 24 steps, both dirs, in-place h ===========
  for (int s = 0; s < 24; s++) {
    short8 aff[8], afb[8];
#pragma unroll
    for (int kt = 0; kt < 8; kt++) {
      aff[kt] = *(const short8*)&hbf[0][u][kt * 32 + kq * 8];
      afb[kt] = *(const short8*)&hbf[1][u][kt * 32 + kq * 8];
    }
    __syncthreads();  // all waves have old h in regs before epilogue writes
#pragma unroll
    for (int dir = 0; dir < 2; dir++) {
      const int pos = dir ? (23 - s) : s;
      const short* WT = dir ? a.WTb : a.WTf;
      const bf16* bias = dir ? a.biasb : a.biasf;
      const bf16* giT = dir ? a.giTabB : a.giTabF;
      const int* srcp = a.src + (size_t)pos * 2048 + r0;
#pragma unroll
      for (int gb = 0; gb < 4; gb++) {
        const int grp = wave * 4 + gb;
        f32x4 g0 = {0.f, 0.f, 0.f, 0.f}, g1 = g0, g2 = g0;
        const short* bp = WT + (size_t)(grp * 64 + u) * 256 + kq * 8;
#pragma unroll
        for (int kt = 0; kt < 8; kt++) {
          const short8 av = dir ? afb[kt] : aff[kt];
          g0 = MFMA(av, *(const short8*)(bp + kt * 32), g0);
          g1 = MFMA(av, *(const short8*)(bp + 16 * 256 + kt * 32), g1);
          g2 = MFMA(av, *(const short8*)(bp + 32 * 256 + kt * 32), g2);
        }
        if (kq == 0) {
          const int i_h = grp * 16 + u;
          const float b0 = to_f(bias[grp * 64 + u]);
          const float b1 = to_f(bias[grp * 64 + 16 + u]);
          const float b2 = to_f(bias[grp * 64 + 32 + u]);
#pragma unroll
          for (int r = 0; r < 4; r++) {
            const int tok = srcp[r];
            const bf16* gp = giT + (size_t)tok * 768 + i_h;
            float ir = to_f(gp[0]), iz = to_f(gp[256]), in_ = to_f(gp[512]);
            float hr = g0[r] + b0, hz = g1[r] + b1, hn = g2[r] + b2;
            float hv = hF[dir][r][i_h];
            float rr = 1.f / (1.f + expf(-(ir + hr)));
            float zz = 1.f / (1.f + expf(-(iz + hz)));
            float nn = tanhf(in_ + rr * hn);
            float o = (1.f - zz) * nn + zz * hv;
            hF[dir][r][i_h] = o;
            short ob = f2b(o);
            hbf[dir][r][i_h] = ob;
            bseL[(pos * 4 + r) * 512 + dir * 256 + i_h] = ob;
          }
        }
      }
    }
    __syncthreads();
  }

  // ====== mid: hidden = tanh([hf|hb]@WT5^T + B5) -> hdF, xr hn-region ====
  {
    short8 af[16];
#pragma unroll
    for (int kt = 0; kt < 8; kt++) {
      af[kt] = *(const short8*)&hbf[0][u][kt * 32 + kq * 8];
      af[8 + kt] = *(const short8*)&hbf[1][u][kt * 32 + kq * 8];
    }
#pragma unroll
    for (int ntl = 0; ntl < 4; ntl++) {
      const int n = wave * 64 + ntl * 16 + u;
      const short* bp = a.WT5 + (size_t)n * 512 + kq * 8;
      f32x4 acc = {0.f, 0.f, 0.f, 0.f};
#pragma unroll
      for (int kt = 0; kt < 16; kt++)
        acc = MFMA(af[kt], *(const short8*)(bp + kt * 32), acc);
      if (kq == 0) {
        const float bv = to_f(a.B5[n]);
#pragma unroll
        for (int r = 0; r < 4; r++) {
          float v_ = tanhf(acc[r] + bv);
          hdF[r][n] = v_;
          xr[r][512 + n] = f2b(v_);
        }
      }
    }
  }
  __syncthreads();  // hbf dead from here; scr may alias it

  // ====== proj = bse@WT6^T + B6 -> 48 VGPRs/lane via LDS scratch ========
  unsigned pr[48];
#pragma unroll
  for (int p = 0; p < 2; p++) {
#pragma unroll
    for (int mt = 0; mt < 3; mt++) {
      short8 af[16];
#pragma unroll
      for (int kt = 0; kt < 16; kt++)
        af[kt] = *(const short8*)&bseL[(p * 48 + mt * 16 + u) * 512 +
                                       kt * 32 + kq * 8];
#pragma unroll
      for (int ntl = 0; ntl < 4; ntl++) {
        const int nt = wave * 4 + ntl;
        const short* bp = a.WT6 + (size_t)(nt * 16 + u) * 512 + kq * 8;
        f32x4 acc = {0.f, 0.f, 0.f, 0.f};
#pragma unroll
        for (int kt = 0; kt < 16; kt++)
          acc = MFMA(af[kt], *(const short8*)(bp + kt * 32), acc);
        const int j = nt * 16 + u;
        const float bv = to_f(a.B6[j]);
#pragma unroll
        for (int r = 0; r < 4; r++) {
          const int f = mt * 16 + kq * 4 + r;
          scr[f & 3][f >> 2][j & 63][j >> 6] = f2b(acc[r] + bv);
        }
      }
    }
    __syncthreads();
#pragma unroll
    for (int sl = 0; sl < 12; sl++) {
      const unsigned* q = (const unsigned*)&scr[wave][sl][lane][0];
      pr[(p * 12 + sl) * 2] = q[0];
      pr[(p * 12 + sl) * 2 + 1] = q[1];
    }
    __syncthreads();
  }

  // ============================ decoder =================================
  const bool isf32 = (*a.dflag != 0u);
  float vv4[4];
#pragma unroll
  for (int c = 0; c < 4; c++) vv4[c] = ldp(a.v, lane + c * 64, isf32);

  // wc: ghw = h @ [dec_Whh|attn_Wh]^T + Bc (A = xr hn-region)
  auto wc_xr = [&]() {
    short8 af[8];
#pragma unroll
    for (int kt = 0; kt < 8; kt++)
      af[kt] = *(const short8*)&xr[u][512 + kt * 32 + kq * 8];
#pragma unroll
    for (int nt = 0; nt < 16; nt++) {
      const int n = wave * 256 + nt * 16 + u;
      const short* bp = a.WcT + (size_t)n * 256 + kq * 8;
      f32x4 acc = {0.f, 0.f, 0.f, 0.f};
#pragma unroll
      for (int kt = 0; kt < 8; kt++)
        acc = MFMA(af[kt], *(const short8*)(bp + kt * 32), acc);
      if (kq == 0) {
        const float bv = to_f(a.Bc[n]);
#pragma unroll
        for (int r = 0; r < 4; r++) ghw[r][n] = f2b(acc[r] + bv);
      }
    }
  };
  wc_xr();
  __syncthreads();

  for (int t = 0; t < 24; t++) {
    const int* trg_t = a.trg + (size_t)t * 2048 + r0;
    // --- energies: wave == row; proj from registers ---
    {
      const int row = wave;
      float hw[4];
#pragma unroll
      for (int c = 0; c < 4; c++) hw[c] = b2f(ghw[row][768 + lane + c * 64]);
#pragma unroll
      for (int s = 0; s < 24; s++) {
        const unsigned q0 = pr[s * 2], q1 = pr[s * 2 + 1];
        float tt = vv4[0] * tanhf(hw[0] + b2f((short)(q0 & 0xffff))) +
                   vv4[1] * tanhf(hw[1] + b2f((short)(q0 >> 16))) +
                   vv4[2] * tanhf(hw[2] + b2f((short)(q1 & 0xffff))) +
                   vv4[3] * tanhf(hw[3] + b2f((short)(q1 >> 16)));
#pragma unroll
        for (int off = 32; off > 0; off >>= 1) tt += __shfl_down(tt, off, 64);
        if (lane == 0) esc[row][s] = tt;
      }
    }
    __syncthreads();
    if (tid < 4) {
      float mx = -1e30f;
      for (int s = 0; s < 24; s++) mx = fmaxf(mx, esc[tid][s]);
      float sm = 0.f;
      for (int s = 0; s < 24; s++) {
        float e = expf(esc[tid][s] - mx);
        aw[tid][s] = e;
        sm += e;
      }
      float inv = 1.f / sm;
      for (int s = 0; s < 24; s++) aw[tid][s] *= inv;
    }
    __syncthreads();
    // --- weighted sum from LDS bse -> xr[:,0:512] ---
    {
      const int row = wave;
      float wv[8];
#pragma unroll
      for (int d = 0; d < 8; d++) wv[d] = 0.f;
      for (int s = 0; s < 24; s++) {
        const float aa = aw[row][s];
        const short* br = &bseL[(s * 4 + row) * 512];
#pragma unroll
        for (int d = 0; d < 8; d++) wv[d] += aa * b2f(br[lane + d * 64]);
      }
#pragma unroll
      for (int d = 0; d < 8; d++) xr[row][lane + d * 64] = f2b(wv[d]);
    }
    __syncthreads();
    // --- cell GEMM (K=512, N=1024 perm) + fused GRU cell ---
    {
      short8 af[16];
#pragma unroll
      for (int kt = 0; kt < 16; kt++)
        af[kt] = *(const short8*)&xr[u][kt * 32 + kq * 8];
#pragma unroll
      for (int gb = 0; gb < 4; gb++) {
        const int grp = wave * 4 + gb;
        f32x4 g0 = {0.f, 0.f, 0.f, 0.f}, g1 = g0, g2 = g0;
        const short* bp = a.W7bT + (size_t)(grp * 64 + u) * 512 + kq * 8;
#pragma unroll
        for (int kt = 0; kt < 16; kt++) {
          g0 = MFMA(af[kt], *(const short8*)(bp + kt * 32), g0);
          g1 = MFMA(af[kt], *(const short8*)(bp + 16 * 512 + kt * 32), g1);
          g2 = MFMA(af[kt], *(const short8*)(bp + 32 * 512 + kt * 32), g2);
        }
        if (kq == 0) {
          const int i_h = grp * 16 + u;
#pragma unroll
          for (int r = 0; r < 4; r++) {
            const int tok = trg_t[r];
            const bf16* gp = a.giTabE + (size_t)tok * 768 + i_h;
            float ir = g0[r] + to_f(gp[0]);
            float iz = g1[r] + to_f(gp[256]);
            float in_ = g2[r] + to_f(gp[512]);
            float hr = b2f(ghw[r][i_h]);
            float hz = b2f(ghw[r][256 + i_h]);
            float hn = b2f(ghw[r][512 + i_h]);
            float hv = hdF[r][i_h];
            float rr2 = 1.f / (1.f + expf(-(ir + hr)));
            float zz = 1.f / (1.f + expf(-(iz + hz)));
            float nn = tanhf(in_ + rr2 * hn);
            float o = (1.f - zz) * nn + zz * hv;
            hdF[r][i_h] = o;
            xr[r][512 + i_h] = f2b(o);
          }
        }
      }
    }
    __syncthreads();
    // --- next-step ghw + logits (disjoint outputs) ---
    if (t < 23) wc_xr();
    {
      f32x4 accL[2] = {{0.f, 0.f, 0.f, 0.f}, {0.f, 0.f, 0.f, 0.f}};
#pragma unroll
      for (int kc = 0; kc < 3; kc++) {
        short8 af[8];
#pragma unroll
        for (int kt = 0; kt < 8; kt++)
          af[kt] = *(const short8*)&xr[u][kc * 256 + kt * 32 + kq * 8];
#pragma unroll
        for (int nt = 0; nt < 2; nt++) {
          const short* bp = a.W8bT + (size_t)(wave * 32 + nt * 16 + u) * 768 +
                            kc * 256 + kq * 8;
#pragma unroll
          for (int kt = 0; kt < 8; kt++)
            accL[nt] = MFMA(af[kt], *(const short8*)(bp + kt * 32), accL[nt]);
        }
      }
      if (kq == 0) {
#pragma unroll
        for (int nt = 0; nt < 2; nt++) {
          const int col = wave * 32 + nt * 16 + u;
#pragma unroll
          for (int r = 0; r < 4; r++) {
            const int tok = trg_t[r];
            a.out[(size_t)(t + 1) * 2048 * 128 + (size_t)(r0 + r) * 128 +
                  col] = accL[nt][r] + a.fcTab[tok * 128 + col];
          }
        }
      }
    }
    __syncthreads();
  }
}

__global__ void sentinel_kernel(float* out, int n) {
  int i = blockIdx.x * 256 + threadIdx.x;
  if (i < n) out[i] = 123.0f;
}

extern "C" void kernel_launch(void* const* d_in, const int* in_sizes, int n_in,
                              void* d_out, int out_size, void* d_ws,
                              size_t ws_size, hipStream_t stream) {
  const int B = 2048, VOUT = 128;
  const int* src = (const int*)d_in[0];
  const int* trg = (const int*)d_in[1];
  const void* enc_emb = d_in[2];
  const void* enc_Wih_f = d_in[3];
  const void* enc_Whh_f = d_in[4];
  const void* enc_bih_f = d_in[5];
  const void* enc_bhh_f = d_in[6];
  const void* enc_Wih_b = d_in[7];
  const void* enc_Whh_b = d_in[8];
  const void* enc_bih_b = d_in[9];
  const void* enc_bhh_b = d_in[10];
  const void* enc_fcW = d_in[11];
  const void* enc_fcb = d_in[12];
  const void* attn_Wh = d_in[13];
  const void* attn_We = d_in[14];
  const void* attn_b = d_in[15];
  const void* attn_v = d_in[16];
  const void* dec_emb = d_in[17];
  const void* dec_Wih = d_in[18];
  const void* dec_Whh = d_in[19];
  const void* dec_bih = d_in[20];
  const void* dec_bhh = d_in[21];
  const void* fcW = d_in[22];
  const void* fcb = d_in[23];
  float* out = (float*)d_out;

  // ---- workspace layout (weights/tables only now) ----
  size_t need = 0;
  auto place = [&](size_t bytes) {
    size_t off = need;
    need += (bytes + 255) & ~(size_t)255;
    return off;
  };
  size_t o_flag = place(256);
  size_t o_wstart = need;
  size_t oEmbE = place(64 * 320 * 2);
  size_t oEmbD = place(128 * 320 * 2);
  size_t oWT1 = place(768 * 320 * 2);
  size_t oWT2 = place(1024 * 256 * 2);
  size_t oWT3 = place(768 * 320 * 2);
  size_t oWT4 = place(1024 * 256 * 2);
  size_t oWT5 = place(256 * 512 * 2);
  size_t oWT6 = place(256 * 512 * 2);
  size_t oWcT = place(1024 * 256 * 2);
  size_t oW7aT = place(768 * 320 * 2);
  size_t oW7bT = place(1024 * 512 * 2);
  size_t oW8aT = place(128 * 320 * 2);
  size_t oW8bT = place(128 * 768 * 2);
  size_t oB1 = place(768 * 2), oB2 = place(1024 * 2);
  size_t oB3 = place(768 * 2), oB4 = place(1024 * 2);
  size_t oB5 = place(256 * 2), oB6 = place(256 * 2);
  size_t oB7 = place(768 * 2), oBc = place(1024 * 2), oB8 = place(128 * 2);
  size_t o_wend = need;
  size_t o_gtF = place(128 * 768 * 2);
  size_t o_gtB = place(128 * 768 * 2);
  size_t o_gtE = place(128 * 768 * 2);
  size_t o_fcT = place(128 * 128 * 4);

  if (ws_size < need) {
    sentinel_kernel<<<(out_size + 255) / 256, 256, 0, stream>>>(out, out_size);
    return;
  }

  char* base = (char*)d_ws;
  unsigned* dflag = (unsigned*)(base + o_flag);
  bf16* embE = (bf16*)(base + oEmbE);
  bf16* embD = (bf16*)(base + oEmbD);
  short* WT1 = (short*)(base + oWT1);
  short* WT2p = (short*)(base + oWT2);
  short* WT3 = (short*)(base + oWT3);
  short* WT4p = (short*)(base + oWT4);
  short* WT5 = (short*)(base + oWT5);
  short* WT6 = (short*)(base + oWT6);
  short* WcT = (short*)(base + oWcT);
  short* W7aT = (short*)(base + oW7aT);
  short* W7bTp = (short*)(base + oW7bT);
  short* W8aT = (short*)(base + oW8aT);
  short* W8bT = (short*)(base + oW8bT);
  bf16 *B1 = (bf16*)(base + oB1), *B2p = (bf16*)(base + oB2);
  bf16 *B3 = (bf16*)(base + oB3), *B4p = (bf16*)(base + oB4);
  bf16 *B5 = (bf16*)(base + oB5), *B6 = (bf16*)(base + oB6);
  bf16 *B7 = (bf16*)(base + oB7), *Bc = (bf16*)(base + oBc);
  bf16* B8 = (bf16*)(base + oB8);
  bf16* giTabF = (bf16*)(base + o_gtF);
  bf16* giTabB = (bf16*)(base + o_gtB);
  bf16* giTabE = (bf16*)(base + o_gtE);
  float* fcTab = (float*)(base + o_fcT);

  detect_kernel<<<1, 256, 0, stream>>>(enc_emb, dflag);
  (void)hipMemsetAsync(base + o_wstart, 0, o_wend - o_wstart, stream);

  // ---- weight prep ----
  PrepArgs pa;
  int ns = 0;
  long long tot = 0;
  auto seg = [&](const void* s, long long soff, short* dst, int scols,
                 int dstride, int transp, long long count) {
    pa.src[ns] = s;
    pa.soff[ns] = soff;
    pa.dst[ns] = dst;
    pa.scols[ns] = scols;
    pa.dstride[ns] = dstride;
    pa.transp[ns] = transp;
    pa.prefix[ns] = tot;
    tot += count;
    ns++;
  };
  seg(enc_emb, 0, (short*)embE, 300, 320, 0, 64 * 300);
  seg(dec_emb, 0, (short*)embD, 300, 320, 0, 128 * 300);
  seg(enc_Wih_f, 0, WT1, 768, 320, 1, 230400);
  seg(enc_Whh_f, 0, WT2p, 768, 256, 2, 196608);
  seg(enc_Wih_b, 0, WT3, 768, 320, 1, 230400);
  seg(enc_Whh_b, 0, WT4p, 768, 256, 2, 196608);
  seg(enc_fcW, 0, WT5, 256, 512, 1, 131072);
  seg(attn_We, 0, WT6, 256, 512, 1, 131072);
  seg(dec_Whh, 0, WcT, 768, 256, 1, 196608);
  seg(attn_Wh, 0, WcT + 768 * 256, 256, 256, 1, 65536);
  seg(dec_Wih, 0, W7aT, 768, 320, 1, 300 * 768);
  seg(dec_Wih, (long long)300 * 768, W7bTp, 768, 512, 2, 512 * 768);
  seg(fcW, (long long)768 * 128, W8aT, 128, 320, 1, 300 * 128);
  seg(fcW, (long long)256 * 128, W8bT, 128, 768, 1, 512 * 128);
  seg(fcW, 0, W8bT + 512, 128, 768, 1, 256 * 128);
  seg(enc_bih_f, 0, (short*)B1, 768, 768, 0, 768);
  seg(enc_bhh_f, 0, (short*)B2p, 768, 1024, 3, 768);
  seg(enc_bih_b, 0, (short*)B3, 768, 768, 0, 768);
  seg(enc_bhh_b, 0, (short*)B4p, 768, 1024, 3, 768);
  seg(enc_fcb, 0, (short*)B5, 256, 256, 0, 256);
  seg(attn_b, 0, (short*)B6, 256, 256, 0, 256);
  seg(dec_bih, 0, (short*)B7, 768, 768, 0, 768);
  seg(dec_bhh, 0, (short*)Bc, 768, 768, 0, 768);  // Bc[768:1024] stays 0
  seg(fcb, 0, (short*)B8, 128, 128, 0, 128);
  pa.prefix[ns] = tot;
  pa.nseg = ns;
  prep_kernel<<<(int)((tot + 255) / 256), 256, 0, stream>>>(pa, dflag);

  (void)hipMemsetAsync(out, 0, (size_t)B * VOUT * 4, stream);  // outputs[0]=0

  // ---- token tables: VIN=64 / VOUT=128 distinct rows only ----
  {
    GJobs a{};
    a.j[0] = {embE, WT1, B1, nullptr, giTabF, 320, 320, 320, 128, 768, 0};
    a.j[1] = {embE, WT3, B3, nullptr, giTabB, 320, 320, 320, 128, 768, 0};
    a.j[2] = {embD, W7aT, B7, nullptr, giTabE, 320, 320, 320, 128, 768, 0};
    a.j[3] = {embD, W8aT, B8, fcTab, nullptr, 320, 320, 320, 128, 128, 0};
    mj_gemm<<<dim3(6, 1, 4), 256, 0, stream>>>(a);
  }

  // ---- whole network: 512 blocks x 4 rows, activations LDS-resident ----
  {
    NetArgs na{WT2p, WT4p, B2p,   B4p,    src,   giTabF, giTabB,
               giTabE, WT5, B5,   WT6,    B6,    WcT,    Bc,
               W7bTp,  W8bT, fcTab, attn_v, dflag, trg,  out};
    net_persist<<<512, 256, 0, stream>>>(na);
  }
}

// Round 8
// 3519.209 us; speedup vs baseline: 2.3065x; 1.4913x over previous
//
#include <hip/hip_runtime.h>
#include <hip/hip_bf16.h>

typedef __hip_bfloat16 bf16;
typedef __attribute__((ext_vector_type(8))) short short8;
typedef __attribute__((ext_vector_type(4))) float f32x4;

#define MFMA(va, vb, vc) \
  __builtin_amdgcn_mfma_f32_16x16x32_bf16(va, vb, vc, 0, 0, 0)

__device__ __forceinline__ float to_f(float x) { return x; }
__device__ __forceinline__ float to_f(bf16 x) { return __bfloat162float(x); }
__device__ __forceinline__ float ldp(const void* p, size_t i, bool f32) {
  return f32 ? ((const float*)p)[i] : __bfloat162float(((const bf16*)p)[i]);
}
__device__ __forceinline__ short f2b(float f) {
  bf16 h = __float2bfloat16(f);
  return *reinterpret_cast<short*>(&h);
}
// gate-interleave permutation (encoder fused cell): c = g*256+i ->
// col' = 64*(i>>4) + 16*g + (i&15). MFMA n-tile == gate.
__device__ __forceinline__ int perm1024(int c) {
  return ((c & 255) >> 4) * 64 + (c >> 8) * 16 + (c & 15);
}

// dtype probe: f32 data read as u16 pairs shows implausible bf16 exponents.
__global__ void detect_kernel(const void* __restrict__ probe,
                              unsigned* __restrict__ flag) {
  __shared__ int sbad;
  if (threadIdx.x == 0) sbad = 0;
  __syncthreads();
  const unsigned short* u = (const unsigned short*)probe;
  int bad = 0;
  for (int i = threadIdx.x; i < 2048; i += 256) {
    unsigned short w = u[i];
    unsigned e = (w >> 7) & 0xFFu;
    bool plaus = (w == 0) || (w == 0x8000u) || (e >= 0x60u && e <= 0x7Eu);
    if (!plaus) bad++;
  }
  atomicAdd(&sbad, bad);
  __syncthreads();
  if (threadIdx.x == 0) *flag = (sbad > 100) ? 1u : 0u;
}

// ---- weight prep: params (f32|bf16) -> bf16 ws ----
// transp: 0=copy, 1=transpose, 2=transpose+perm1024, 3=copy+perm1024
#define MAXSEG 24
struct PrepArgs {
  int nseg;
  const void* src[MAXSEG];
  long long soff[MAXSEG];
  short* dst[MAXSEG];
  int scols[MAXSEG];
  int dstride[MAXSEG];
  int transp[MAXSEG];
  long long prefix[MAXSEG + 1];
};
__global__ void prep_kernel(PrepArgs a, const unsigned* __restrict__ dflag) {
  const bool isf32 = (*dflag != 0u);
  long long i = (long long)blockIdx.x * 256 + threadIdx.x;
  if (i >= a.prefix[a.nseg]) return;
  int s = 0;
  while (i >= a.prefix[s + 1]) s++;
  long long loc = i - a.prefix[s];
  long long r = loc / a.scols[s], c = loc % a.scols[s];
  float v = a.src[s] ? ldp(a.src[s], (size_t)(a.soff[s] + loc), isf32) : 0.f;
  int tp = a.transp[s];
  long long idx;
  if (tp == 1)
    idx = c * a.dstride[s] + r;
  else if (tp == 2)
    idx = (long long)perm1024((int)c) * a.dstride[s] + r;
  else if (tp == 3)
    idx = perm1024((int)c);
  else
    idx = r * a.dstride[s] + c;
  a.dst[s][idx] = f2b(v);
}

// ---- multi-job MFMA GEMM, 128x128 tile (tables, mid, wc0) ----
struct GJob {
  const bf16* A;
  const short* WT;
  const bf16* bias;
  float* Cf;
  bf16* Ch;
  int lda, wst, K, M, N, flags;  // flags: 4=tanh
};
struct GJobs {
  GJob j[4];
};

__global__ __launch_bounds__(256) void mj_gemm(GJobs args) {
  GJob jb = args.j[blockIdx.z];
  const int n0 = blockIdx.x * 128, m0 = blockIdx.y * 128;
  if (n0 >= jb.N || m0 >= jb.M) return;
  __shared__ short As[128][40];
  __shared__ short Bs[128][40];
  const int tid = threadIdx.x, lane = tid & 63, wave = tid >> 6;
  const int srow = tid >> 1, skoff = (tid & 1) * 16;
  const int wr = (wave >> 1) * 64, wc = (wave & 1) * 64;

  const short* abase =
      (const short*)jb.A + (long long)(m0 + srow) * jb.lda + skoff;
  const short* bbase = jb.WT + (long long)(n0 + srow) * jb.wst + skoff;
  f32x4 acc[4][4];
#pragma unroll
  for (int i = 0; i < 4; i++)
#pragma unroll
    for (int j = 0; j < 4; j++) acc[i][j] = 0.f;

  short8 a0 = *(const short8*)(abase);
  short8 a1 = *(const short8*)(abase + 8);
  short8 b0 = *(const short8*)(bbase);
  short8 b1 = *(const short8*)(bbase + 8);
  for (int k0 = 0; k0 < jb.K; k0 += 32) {
    __syncthreads();
    *(short8*)&As[srow][skoff] = a0;
    *(short8*)&As[srow][skoff + 8] = a1;
    *(short8*)&Bs[srow][skoff] = b0;
    *(short8*)&Bs[srow][skoff + 8] = b1;
    __syncthreads();
    int kn = (k0 + 32 < jb.K) ? k0 + 32 : k0;  // clamped prefetch
    a0 = *(const short8*)(abase + kn);
    a1 = *(const short8*)(abase + kn + 8);
    b0 = *(const short8*)(bbase + kn);
    b1 = *(const short8*)(bbase + kn + 8);
    short8 af[4], bfr[4];
#pragma unroll
    for (int i = 0; i < 4; i++)
      af[i] = *(short8*)&As[wr + i * 16 + (lane & 15)][(lane >> 4) * 8];
#pragma unroll
    for (int j = 0; j < 4; j++)
      bfr[j] = *(short8*)&Bs[wc + j * 16 + (lane & 15)][(lane >> 4) * 8];
#pragma unroll
    for (int i = 0; i < 4; i++)
#pragma unroll
      for (int j = 0; j < 4; j++) acc[i][j] = MFMA(af[i], bfr[j], acc[i][j]);
  }
  const int N = jb.N;
#pragma unroll
  for (int j = 0; j < 4; j++) {
    int col = n0 + wc + j * 16 + (lane & 15);
    float bv = jb.bias ? to_f(jb.bias[col]) : 0.f;
#pragma unroll
    for (int i = 0; i < 4; i++) {
#pragma unroll
      for (int r = 0; r < 4; r++) {
        int row = m0 + wr + i * 16 + (lane >> 4) * 4 + r;
        float v = acc[i][j][r] + bv;
        if (jb.flags & 4) v = tanhf(v);
        if (jb.Cf) jb.Cf[(long long)row * N + col] = v;
        if (jb.Ch) jb.Ch[(long long)row * N + col] = __float2bfloat16(v);
      }
    }
  }
}

// ---- encoder fused GEMM + GRU cell (round-2 proven kernel) ----
// N'=1024 gate-interleaved (perm1024), acc frag j = gate.
struct CJob {
  const bf16* A;
  const short* WT;
  const bf16* bias;
  const int* tok;
  const bf16* giTab;  // [vocab][768] gate-major (incl bih)
  float* hF;
  bf16* hBf;
  bf16* out2;  // bse slice
  long long out2s;
  int lda, wst, K, hstride, hoff;
};
struct CJobs {
  CJob j[2];
};

__global__ __launch_bounds__(256) void mj_gemm_cell(CJobs args) {
  CJob jb = args.j[blockIdx.z];
  const int n0 = blockIdx.x * 128, m0 = blockIdx.y * 128;
  __shared__ short As[128][40];
  __shared__ short Bs[128][40];
  __shared__ int toks[128];
  const int tid = threadIdx.x, lane = tid & 63, wave = tid >> 6;
  const int srow = tid >> 1, skoff = (tid & 1) * 16;
  const int wr = (wave >> 1) * 64, wcq = (wave & 1) * 64;

  if (tid < 128) toks[tid] = jb.tok[m0 + tid];
  const short* abase =
      (const short*)jb.A + (long long)(m0 + srow) * jb.lda + skoff;
  const short* bbase = jb.WT + (long long)(n0 + srow) * jb.wst + skoff;

  f32x4 acc[4][4];
#pragma unroll
  for (int i = 0; i < 4; i++)
#pragma unroll
    for (int j = 0; j < 4; j++) acc[i][j] = 0.f;

  short8 a0 = *(const short8*)(abase);
  short8 a1 = *(const short8*)(abase + 8);
  short8 b0 = *(const short8*)(bbase);
  short8 b1 = *(const short8*)(bbase + 8);
  for (int k0 = 0; k0 < jb.K; k0 += 32) {
    __syncthreads();
    *(short8*)&As[srow][skoff] = a0;
    *(short8*)&As[srow][skoff + 8] = a1;
    *(short8*)&Bs[srow][skoff] = b0;
    *(short8*)&Bs[srow][skoff + 8] = b1;
    __syncthreads();
    int kn = (k0 + 32 < jb.K) ? k0 + 32 : k0;
    a0 = *(const short8*)(abase + kn);
    a1 = *(const short8*)(abase + kn + 8);
    b0 = *(const short8*)(bbase + kn);
    b1 = *(const short8*)(bbase + kn + 8);
    short8 af[4], bfr[4];
#pragma unroll
    for (int i = 0; i < 4; i++)
      af[i] = *(short8*)&As[wr + i * 16 + (lane & 15)][(lane >> 4) * 8];
#pragma unroll
    for (int j = 0; j < 4; j++)
      bfr[j] = *(short8*)&Bs[wcq + j * 16 + (lane & 15)][(lane >> 4) * 8];
#pragma unroll
    for (int i = 0; i < 4; i++)
#pragma unroll
      for (int j = 0; j < 4; j++) acc[i][j] = MFMA(af[i], bfr[j], acc[i][j]);
  }

  const int u = lane & 15, hi4 = (lane >> 4) * 4;
  const int i_h = ((n0 + wcq) >> 6) * 16 + u;
  const float b0g = to_f(jb.bias[n0 + wcq + u]);
  const float b1g = to_f(jb.bias[n0 + wcq + 16 + u]);
  const float b2g = to_f(jb.bias[n0 + wcq + 32 + u]);
#pragma unroll
  for (int i = 0; i < 4; i++) {
#pragma unroll
    for (int r = 0; r < 4; r++) {
      int row = m0 + wr + i * 16 + hi4 + r;
      const bf16* gi = jb.giTab + (long long)toks[row - m0] * 768 + i_h;
      float ir = to_f(gi[0]), iz = to_f(gi[256]), in_ = to_f(gi[512]);
      float hr = acc[i][0][r] + b0g;
      float hz = acc[i][1][r] + b1g;
      float hn = acc[i][2][r] + b2g;
      long long hidx = (long long)row * jb.hstride + jb.hoff + i_h;
      float hv = jb.hF[hidx];
      float rr = 1.f / (1.f + expf(-(ir + hr)));
      float zz = 1.f / (1.f + expf(-(iz + hz)));
      float nn = tanhf(in_ + rr * hn);
      float o = (1.f - zz) * nn + zz * hv;
      jb.hF[hidx] = o;
      jb.hBf[hidx] = __float2bfloat16(o);
      jb.out2[(long long)row * jb.out2s + i_h] = __float2bfloat16(o);
    }
  }
}

// ---- attention + P7/P8w reductions. One block per batch row. ----
// aw = softmax(v . tanh(hWh + proj)); gi_dyn = sum aw*P7; l8 = sum aw*P8w.
struct AttnPArgs {
  const bf16* ghw;   // [2048][1024] current (cols 768:1024 = hWh)
  const bf16* proj;  // [2048*24][256]
  const bf16* P7;    // [2048*24][768]
  const bf16* P8w;   // [2048*24][128]
  const void* v;
  const unsigned* dflag;
  bf16* gi_dyn;  // [2048][768]
  float* l8;     // [2048][128]
};
__global__ __launch_bounds__(256) void attnp_kernel(AttnPArgs a) {
  int b = blockIdx.x, tid = threadIdx.x;
  int wave = tid >> 6, lane = tid & 63;
  __shared__ float partial[24][4];
  __shared__ float aw[24];
  const bool isf32 = (*a.dflag != 0u);
  float vh = to_f(a.ghw[(long long)b * 1024 + 768 + tid]);
  float vv = ldp(a.v, tid, isf32);
  const bf16* pb = a.proj + (long long)b * 24 * 256;
#pragma unroll 4
  for (int s = 0; s < 24; s++) {
    float e = tanhf(vh + to_f(pb[s * 256 + tid]));
    float t = vv * e;
#pragma unroll
    for (int off = 32; off > 0; off >>= 1) t += __shfl_down(t, off, 64);
    if (lane == 0) partial[s][wave] = t;
  }
  __syncthreads();
  if (tid == 0) {
    float sc[24];
    float mx = -1e30f;
    for (int s = 0; s < 24; s++) {
      float xv = partial[s][0] + partial[s][1] + partial[s][2] + partial[s][3];
      sc[s] = xv;
      mx = fmaxf(mx, xv);
    }
    float sum = 0.f;
    for (int s = 0; s < 24; s++) {
      sc[s] = expf(sc[s] - mx);
      sum += sc[s];
    }
    float inv = 1.f / sum;
    for (int s = 0; s < 24; s++) aw[s] = sc[s] * inv;
  }
  __syncthreads();
  const bf16* p7 = a.P7 + (long long)b * 24 * 768;
  float g0 = 0.f, g1 = 0.f, g2 = 0.f;
#pragma unroll 4
  for (int s = 0; s < 24; s++) {
    float aa = aw[s];
    g0 += aa * to_f(p7[s * 768 + tid]);
    g1 += aa * to_f(p7[s * 768 + 256 + tid]);
    g2 += aa * to_f(p7[s * 768 + 512 + tid]);
  }
  bf16* gd = a.gi_dyn + (long long)b * 768;
  gd[tid] = __float2bfloat16(g0);
  gd[256 + tid] = __float2bfloat16(g1);
  gd[512 + tid] = __float2bfloat16(g2);
  if (tid < 128) {
    const bf16* p8 = a.P8w + (long long)b * 24 * 128;
    float l = 0.f;
#pragma unroll 4
    for (int s = 0; s < 24; s++) l += aw[s] * to_f(p8[s * 128 + tid]);
    a.l8[(long long)b * 128 + tid] = l;
  }
}

// ---- fused GRU cell + [wc | logits] GEMM. grid (9, 16). ----
// front: h_new for block's 128 rows (elementwise, in LDS). Then
// C = h_new @ [WcT(1024) | W8hn(128)]^T, K=256. cols<1024 -> ghw_out+Bc;
// cols>=1024 -> out[t+1] = acc + l8 + fcTab[tok].
struct CWArgs {
  const bf16* gi_dyn;  // [2048][768]
  const bf16* giTabE;  // [128][768] incl bih
  const bf16* ghw_in;  // [2048][1024]
  bf16* ghw_out;       // [2048][1024]
  const float* hd_in;  // [2048][256]
  float* hd_out;       // [2048][256]
  const short* WcT;    // [1024][256]
  const bf16* Bc;      // [1024]
  const short* W8hn;   // [128][256]
  const float* l8;     // [2048][128]
  const float* fcTab;  // [128][128]
  const int* trg_t;
  float* outT;  // out + (t+1)*2048*128
};
__global__ __launch_bounds__(256) void cellwc_kernel(CWArgs a) {
  const int n0 = blockIdx.x * 128;  // 0..1151
  const int m0 = blockIdx.y * 128;
  const int tid = threadIdx.x, lane = tid & 63, wave = tid >> 6;
  const int u = lane & 15, kq = lane >> 4;
  __shared__ short hA[128][264];
  __shared__ int toks[128];
  if (tid < 128) toks[tid] = a.trg_t[m0 + tid];
  __syncthreads();
  // front: dim d = tid, all 128 rows
  const int d = tid;
#pragma unroll 2
  for (int r = 0; r < 128; r++) {
    const int row = m0 + r;
    const bf16* gd = a.gi_dyn + (long long)row * 768;
    const bf16* ge = a.giTabE + (long long)toks[r] * 768;
    const bf16* gh = a.ghw_in + (long long)row * 1024;
    float ir = to_f(gd[d]) + to_f(ge[d]);
    float iz = to_f(gd[256 + d]) + to_f(ge[256 + d]);
    float in_ = to_f(gd[512 + d]) + to_f(ge[512 + d]);
    float hr = to_f(gh[d]), hz = to_f(gh[256 + d]), hn = to_f(gh[512 + d]);
    float hv = a.hd_in[(long long)row * 256 + d];
    float rr = 1.f / (1.f + expf(-(ir + hr)));
    float zz = 1.f / (1.f + expf(-(iz + hz)));
    float nn = tanhf(in_ + rr * hn);
    float o = (1.f - zz) * nn + zz * hv;
    hA[r][d] = f2b(o);
    if (n0 == 0) a.hd_out[(long long)row * 256 + d] = o;
  }
  __syncthreads();
  // GEMM: wave owns 32 cols (2 tiles of 16)
#pragma unroll
  for (int nt = 0; nt < 2; nt++) {
    const int n = n0 + wave * 32 + nt * 16 + u;
    const short* bp = (n < 1024)
                          ? a.WcT + (size_t)n * 256 + kq * 8
                          : a.W8hn + (size_t)(n - 1024) * 256 + kq * 8;
    short8 bfr[8];
#pragma unroll
    for (int kt = 0; kt < 8; kt++) bfr[kt] = *(const short8*)(bp + kt * 32);
    const bool iswc = (n0 + wave * 32 + nt * 16) < 1024;
    const float bv = iswc ? to_f(a.Bc[n]) : 0.f;
#pragma unroll
    for (int mt = 0; mt < 8; mt++) {
      f32x4 acc = {0.f, 0.f, 0.f, 0.f};
#pragma unroll
      for (int kt = 0; kt < 8; kt++)
        acc = MFMA(*(const short8*)&hA[mt * 16 + u][kt * 32 + kq * 8],
                   bfr[kt], acc);
#pragma unroll
      for (int r = 0; r < 4; r++) {
        const int rl = mt * 16 + kq * 4 + r;
        const int row = m0 + rl;
        if (iswc) {
          a.ghw_out[(long long)row * 1024 + n] = __float2bfloat16(acc[r] + bv);
        } else {
          const int c = n - 1024;
          a.outT[(long long)row * 128 + c] =
              acc[r] + a.l8[(long long)row * 128 + c] +
              a.fcTab[toks[rl] * 128 + c];
        }
      }
    }
  }
}

__global__ void sentinel_kernel(float* out, int n) {
  int i = blockIdx.x * 256 + threadIdx.x;
  if (i < n) out[i] = 123.0f;
}

extern "C" void kernel_launch(void* const* d_in, const int* in_sizes, int n_in,
                              void* d_out, int out_size, void* d_ws,
                              size_t ws_size, hipStream_t stream) {
  const int B = 2048, S = 24, T = 25, VOUT = 128;
  const int* src = (const int*)d_in[0];
  const int* trg = (const int*)d_in[1];
  const void* enc_emb = d_in[2];
  const void* enc_Wih_f = d_in[3];
  const void* enc_Whh_f = d_in[4];
  const void* enc_bih_f = d_in[5];
  const void* enc_bhh_f = d_in[6];
  const void* enc_Wih_b = d_in[7];
  const void* enc_Whh_b = d_in[8];
  const void* enc_bih_b = d_in[9];
  const void* enc_bhh_b = d_in[10];
  const void* enc_fcW = d_in[11];
  const void* enc_fcb = d_in[12];
  const void* attn_Wh = d_in[13];
  const void* attn_We = d_in[14];
  const void* attn_b = d_in[15];
  const void* attn_v = d_in[16];
  const void* dec_emb = d_in[17];
  const void* dec_Wih = d_in[18];
  const void* dec_Whh = d_in[19];
  const void* dec_bih = d_in[20];
  const void* dec_bhh = d_in[21];
  const void* fcW = d_in[22];
  const void* fcb = d_in[23];
  float* out = (float*)d_out;

  // ---- workspace layout ----
  size_t need = 0;
  auto place = [&](size_t bytes) {
    size_t off = need;
    need += (bytes + 255) & ~(size_t)255;
    return off;
  };
  size_t o_flag = place(256);
  size_t o_wstart = need;  // memset-0 region
  size_t oEmbE = place(64 * 320 * 2);
  size_t oEmbD = place(128 * 320 * 2);
  size_t oWT1 = place(768 * 320 * 2);    // enc_Wih_f^T
  size_t oWT2 = place(1024 * 256 * 2);   // enc_Whh_f^T perm
  size_t oWT3 = place(768 * 320 * 2);    // enc_Wih_b^T
  size_t oWT4 = place(1024 * 256 * 2);   // enc_Whh_b^T perm
  size_t oWT5 = place(256 * 512 * 2);    // enc_fcW^T
  size_t oWT6 = place(256 * 512 * 2);    // attn_We^T
  size_t oWcT = place(1024 * 256 * 2);   // [dec_Whh | attn_Wh]^T
  size_t oW7aT = place(768 * 320 * 2);   // dec_Wih[0:300]^T
  size_t oW7bT = place(768 * 512 * 2);   // dec_Wih[300:812]^T (plain)
  size_t oW8aT = place(128 * 320 * 2);   // fcW emb rows^T
  size_t oW8wT = place(128 * 512 * 2);   // fcW weighted rows^T
  size_t oW8hn = place(128 * 256 * 2);   // fcW hn rows^T
  size_t oB1 = place(768 * 2), oB2 = place(1024 * 2);
  size_t oB3 = place(768 * 2), oB4 = place(1024 * 2);
  size_t oB5 = place(256 * 2), oB6 = place(256 * 2);
  size_t oB7 = place(768 * 2), oBc = place(1024 * 2), oB8 = place(128 * 2);
  size_t o_wend = need;
  size_t o_bse = place((size_t)B * S * 512 * 2);
  size_t o_proj = place((size_t)B * S * 256 * 2);
  size_t o_P7 = place((size_t)B * S * 768 * 2);   // 75.5 MB
  size_t o_P8 = place((size_t)B * S * 128 * 2);   // 12.6 MB
  size_t o_ghw0 = place((size_t)B * 1024 * 2);
  size_t o_ghw1 = place((size_t)B * 1024 * 2);
  size_t o_hfb = place((size_t)B * 512 * 4);
  size_t o_hb0 = place((size_t)B * 512 * 2);
  size_t o_hb1 = place((size_t)B * 512 * 2);
  size_t o_hd0 = place((size_t)B * 256 * 4);
  size_t o_hd1 = place((size_t)B * 256 * 4);
  size_t o_hdbf = place((size_t)B * 256 * 2);
  size_t o_gid = place((size_t)B * 768 * 2);
  size_t o_l8 = place((size_t)B * 128 * 4);
  size_t o_gtF = place(128 * 768 * 2);
  size_t o_gtB = place(128 * 768 * 2);
  size_t o_gtE = place(128 * 768 * 2);
  size_t o_fcT = place(128 * 128 * 4);

  if (ws_size < need) {
    sentinel_kernel<<<(out_size + 255) / 256, 256, 0, stream>>>(out, out_size);
    return;
  }

  char* base = (char*)d_ws;
  unsigned* dflag = (unsigned*)(base + o_flag);
  bf16* embE = (bf16*)(base + oEmbE);
  bf16* embD = (bf16*)(base + oEmbD);
  short* WT1 = (short*)(base + oWT1);
  short* WT2p = (short*)(base + oWT2);
  short* WT3 = (short*)(base + oWT3);
  short* WT4p = (short*)(base + oWT4);
  short* WT5 = (short*)(base + oWT5);
  short* WT6 = (short*)(base + oWT6);
  short* WcT = (short*)(base + oWcT);
  short* W7aT = (short*)(base + oW7aT);
  short* W7bT = (short*)(base + oW7bT);
  short* W8aT = (short*)(base + oW8aT);
  short* W8wT = (short*)(base + oW8wT);
  short* W8hn = (short*)(base + oW8hn);
  bf16 *B1 = (bf16*)(base + oB1), *B2p = (bf16*)(base + oB2);
  bf16 *B3 = (bf16*)(base + oB3), *B4p = (bf16*)(base + oB4);
  bf16 *B5 = (bf16*)(base + oB5), *B6 = (bf16*)(base + oB6);
  bf16 *B7 = (bf16*)(base + oB7), *Bc = (bf16*)(base + oBc);
  bf16* B8 = (bf16*)(base + oB8);
  bf16* bse = (bf16*)(base + o_bse);
  bf16* proj = (bf16*)(base + o_proj);
  bf16* P7 = (bf16*)(base + o_P7);
  bf16* P8w = (bf16*)(base + o_P8);
  bf16* ghw[2] = {(bf16*)(base + o_ghw0), (bf16*)(base + o_ghw1)};
  float* hfb = (float*)(base + o_hfb);
  bf16* hb[2] = {(bf16*)(base + o_hb0), (bf16*)(base + o_hb1)};
  float* h_d[2] = {(float*)(base + o_hd0), (float*)(base + o_hd1)};
  bf16* hdbf = (bf16*)(base + o_hdbf);
  bf16* gi_dyn = (bf16*)(base + o_gid);
  float* l8 = (float*)(base + o_l8);
  bf16* giTabF = (bf16*)(base + o_gtF);
  bf16* giTabB = (bf16*)(base + o_gtB);
  bf16* giTabE = (bf16*)(base + o_gtE);
  float* fcTab = (float*)(base + o_fcT);

  detect_kernel<<<1, 256, 0, stream>>>(enc_emb, dflag);
  (void)hipMemsetAsync(base + o_wstart, 0, o_wend - o_wstart, stream);

  // ---- weight prep ----
  PrepArgs pa;
  int ns = 0;
  long long tot = 0;
  auto seg = [&](const void* s, long long soff, short* dst, int scols,
                 int dstride, int transp, long long count) {
    pa.src[ns] = s;
    pa.soff[ns] = soff;
    pa.dst[ns] = dst;
    pa.scols[ns] = scols;
    pa.dstride[ns] = dstride;
    pa.transp[ns] = transp;
    pa.prefix[ns] = tot;
    tot += count;
    ns++;
  };
  seg(enc_emb, 0, (short*)embE, 300, 320, 0, 64 * 300);
  seg(dec_emb, 0, (short*)embD, 300, 320, 0, 128 * 300);
  seg(enc_Wih_f, 0, WT1, 768, 320, 1, 230400);
  seg(enc_Whh_f, 0, WT2p, 768, 256, 2, 196608);
  seg(enc_Wih_b, 0, WT3, 768, 320, 1, 230400);
  seg(enc_Whh_b, 0, WT4p, 768, 256, 2, 196608);
  seg(enc_fcW, 0, WT5, 256, 512, 1, 131072);
  seg(attn_We, 0, WT6, 256, 512, 1, 131072);
  seg(dec_Whh, 0, WcT, 768, 256, 1, 196608);
  seg(attn_Wh, 0, WcT + 768 * 256, 256, 256, 1, 65536);
  seg(dec_Wih, 0, W7aT, 768, 320, 1, 300 * 768);                     // 0:300
  seg(dec_Wih, (long long)300 * 768, W7bT, 768, 512, 1, 512 * 768);  // rest
  seg(fcW, (long long)768 * 128, W8aT, 128, 320, 1, 300 * 128);  // emb
  seg(fcW, (long long)256 * 128, W8wT, 128, 512, 1, 512 * 128);  // weighted
  seg(fcW, 0, W8hn, 128, 256, 1, 256 * 128);                     // hn
  seg(enc_bih_f, 0, (short*)B1, 768, 768, 0, 768);
  seg(enc_bhh_f, 0, (short*)B2p, 768, 1024, 3, 768);
  seg(enc_bih_b, 0, (short*)B3, 768, 768, 0, 768);
  seg(enc_bhh_b, 0, (short*)B4p, 768, 1024, 3, 768);
  seg(enc_fcb, 0, (short*)B5, 256, 256, 0, 256);
  seg(attn_b, 0, (short*)B6, 256, 256, 0, 256);
  seg(dec_bih, 0, (short*)B7, 768, 768, 0, 768);
  seg(dec_bhh, 0, (short*)Bc, 768, 768, 0, 768);  // Bc[768:1024] stays 0
  seg(fcb, 0, (short*)B8, 128, 128, 0, 128);
  pa.prefix[ns] = tot;
  pa.nseg = ns;
  prep_kernel<<<(int)((tot + 255) / 256), 256, 0, stream>>>(pa, dflag);

  (void)hipMemsetAsync(hfb, 0, (size_t)B * 512 * 4, stream);
  (void)hipMemsetAsync(hb[0], 0, (size_t)B * 512 * 2, stream);
  (void)hipMemsetAsync(out, 0, (size_t)B * VOUT * 4, stream);  // outputs[0]=0

  auto launch = [&](const GJob* jobs, int nj, int gx, int gy) {
    GJobs a{};
    for (int i = 0; i < nj; i++) a.j[i] = jobs[i];
    mj_gemm<<<dim3(gx, gy, nj), 256, 0, stream>>>(a);
  };

  // ---- token tables ----
  {
    GJob tj[4];
    tj[0] = {embE, WT1, B1, nullptr, giTabF, 320, 320, 320, 128, 768, 0};
    tj[1] = {embE, WT3, B3, nullptr, giTabB, 320, 320, 320, 128, 768, 0};
    tj[2] = {embD, W7aT, B7, nullptr, giTabE, 320, 320, 320, 128, 768, 0};
    tj[3] = {embD, W8aT, B8, fcTab, nullptr, 320, 320, 320, 128, 128, 0};
    launch(tj, 4, 6, 1);
  }

  // ---- encoder: one fused launch per step (round-2 proven) ----
  for (int s = 0; s < S; s++) {
    CJobs ca{};
    ca.j[0] = {hb[s & 1], WT2p, B2p, src + (size_t)s * B, giTabF,
               hfb, hb[(s + 1) & 1], bse + (size_t)s * 512, 12288,
               512, 256, 256, 512, 0};
    ca.j[1] = {hb[s & 1] + 256, WT4p, B4p, src + (size_t)(S - 1 - s) * B,
               giTabB, hfb, hb[(s + 1) & 1],
               bse + (size_t)(S - 1 - s) * 512 + 256, 12288,
               512, 256, 256, 512, 256};
    mj_gemm_cell<<<dim3(8, 16, 2), 256, 0, stream>>>(ca);
  }

  // ---- mid: hidden, proj, P7, P8w in one batched launch ----
  {
    GJob mj[4];
    mj[0] = {hb[0], WT5, B5, h_d[0], hdbf, 512, 512, 512, B, 256, 4};
    mj[1] = {bse, WT6, B6, nullptr, proj, 512, 512, 512, B * S, 256, 0};
    mj[2] = {bse, W7bT, nullptr, nullptr, P7, 512, 512, 512, B * S, 768, 0};
    mj[3] = {bse, W8wT, nullptr, nullptr, P8w, 512, 512, 512, B * S, 128, 0};
    launch(mj, 4, 6, 384);
  }
  // initial ghw[0] = hdbf @ [dec_Whh|attn_Wh]^T + Bc
  {
    GJob j0 = {hdbf, WcT, Bc, nullptr, ghw[0], 256, 256, 256, B, 1024, 0};
    launch(&j0, 1, 8, 16);
  }

  // ---- decoder: 2 launches per step ----
  for (int t = 0; t < T - 1; t++) {
    AttnPArgs aa{ghw[t & 1], proj, P7, P8w, attn_v, dflag, gi_dyn, l8};
    attnp_kernel<<<B, 256, 0, stream>>>(aa);
    CWArgs cw{gi_dyn,      giTabE, ghw[t & 1],  ghw[(t + 1) & 1],
              h_d[t & 1],  h_d[(t + 1) & 1],    WcT,  Bc,
              W8hn,        l8,     fcTab,       trg + (size_t)t * B,
              out + (size_t)(t + 1) * B * VOUT};
    cellwc_kernel<<<dim3(9, 16), 256, 0, stream>>>(cw);
  }
}

// Round 9
// 2676.359 us; speedup vs baseline: 3.0329x; 1.3149x over previous
//
#include <hip/hip_runtime.h>
#include <hip/hip_bf16.h>

typedef __hip_bfloat16 bf16;
typedef __attribute__((ext_vector_type(8))) short short8;
typedef __attribute__((ext_vector_type(4))) float f32x4;

#define MFMA(va, vb, vc) \
  __builtin_amdgcn_mfma_f32_16x16x32_bf16(va, vb, vc, 0, 0, 0)

__device__ __forceinline__ float to_f(float x) { return x; }
__device__ __forceinline__ float to_f(bf16 x) { return __bfloat162float(x); }
__device__ __forceinline__ float ldp(const void* p, size_t i, bool f32) {
  return f32 ? ((const float*)p)[i] : __bfloat162float(((const bf16*)p)[i]);
}
__device__ __forceinline__ short f2b(float f) {
  bf16 h = __float2bfloat16(f);
  return *reinterpret_cast<short*>(&h);
}
__device__ __forceinline__ float b2f(short s_) {
  unsigned int ui = ((unsigned int)(unsigned short)s_) << 16;
  float f;
  __builtin_memcpy(&f, &ui, 4);
  return f;
}
// gate-interleave permutation: c = g*256+i -> 64*(i>>4) + 16*g + (i&15).
// MFMA n-subtile j == gate in fused cell kernels.
__device__ __forceinline__ int perm1024(int c) {
  return ((c & 255) >> 4) * 64 + (c >> 8) * 16 + (c & 15);
}

// dtype probe: f32 data read as u16 pairs shows implausible bf16 exponents.
__global__ void detect_kernel(const void* __restrict__ probe,
                              unsigned* __restrict__ flag) {
  __shared__ int sbad;
  if (threadIdx.x == 0) sbad = 0;
  __syncthreads();
  const unsigned short* u = (const unsigned short*)probe;
  int bad = 0;
  for (int i = threadIdx.x; i < 2048; i += 256) {
    unsigned short w = u[i];
    unsigned e = (w >> 7) & 0xFFu;
    bool plaus = (w == 0) || (w == 0x8000u) || (e >= 0x60u && e <= 0x7Eu);
    if (!plaus) bad++;
  }
  atomicAdd(&sbad, bad);
  __syncthreads();
  if (threadIdx.x == 0) *flag = (sbad > 100) ? 1u : 0u;
}

// ---- weight prep ----
// transp: 0=copy, 1=transpose, 2=transpose+perm1024, 3=copy+perm1024
#define MAXSEG 24
struct PrepArgs {
  int nseg;
  const void* src[MAXSEG];
  long long soff[MAXSEG];
  short* dst[MAXSEG];
  int scols[MAXSEG];
  int dstride[MAXSEG];
  int transp[MAXSEG];
  long long prefix[MAXSEG + 1];
};
__global__ void prep_kernel(PrepArgs a, const unsigned* __restrict__ dflag) {
  const bool isf32 = (*dflag != 0u);
  long long i = (long long)blockIdx.x * 256 + threadIdx.x;
  if (i >= a.prefix[a.nseg]) return;
  int s = 0;
  while (i >= a.prefix[s + 1]) s++;
  long long loc = i - a.prefix[s];
  long long r = loc / a.scols[s], c = loc % a.scols[s];
  float v = a.src[s] ? ldp(a.src[s], (size_t)(a.soff[s] + loc), isf32) : 0.f;
  int tp = a.transp[s];
  long long idx;
  if (tp == 1)
    idx = c * a.dstride[s] + r;
  else if (tp == 2)
    idx = (long long)perm1024((int)c) * a.dstride[s] + r;
  else if (tp == 3)
    idx = perm1024((int)c);
  else
    idx = r * a.dstride[s] + c;
  a.dst[s][idx] = f2b(v);
}

// ---- multi-job MFMA GEMM, 128x128 tile (tables, mid, logits) ----
struct GJob {
  const bf16* A;
  const short* WT;
  const bf16* bias;
  float* Cf;
  bf16* Ch;
  const float* Cin;   // optional f32 addend, stride N
  const int* cinrow;  // optional row gather for Cin
  int lda, wst, K, M, N, flags;  // flags: 4=tanh
};
struct GJobs {
  GJob j[4];
};

__global__ __launch_bounds__(256) void mj_gemm(GJobs args) {
  GJob jb = args.j[blockIdx.z];
  const int n0 = blockIdx.x * 128, m0 = blockIdx.y * 128;
  if (n0 >= jb.N || m0 >= jb.M) return;
  __shared__ short As[128][40];
  __shared__ short Bs[128][40];
  const int tid = threadIdx.x, lane = tid & 63, wave = tid >> 6;
  const int srow = tid >> 1, skoff = (tid & 1) * 16;
  const int wr = (wave >> 1) * 64, wc = (wave & 1) * 64;

  const short* abase =
      (const short*)jb.A + (long long)(m0 + srow) * jb.lda + skoff;
  const short* bbase = jb.WT + (long long)(n0 + srow) * jb.wst + skoff;
  f32x4 acc[4][4];
#pragma unroll
  for (int i = 0; i < 4; i++)
#pragma unroll
    for (int j = 0; j < 4; j++) acc[i][j] = 0.f;

  short8 a0 = *(const short8*)(abase);
  short8 a1 = *(const short8*)(abase + 8);
  short8 b0 = *(const short8*)(bbase);
  short8 b1 = *(const short8*)(bbase + 8);
  for (int k0 = 0; k0 < jb.K; k0 += 32) {
    __syncthreads();
    *(short8*)&As[srow][skoff] = a0;
    *(short8*)&As[srow][skoff + 8] = a1;
    *(short8*)&Bs[srow][skoff] = b0;
    *(short8*)&Bs[srow][skoff + 8] = b1;
    __syncthreads();
    int kn = (k0 + 32 < jb.K) ? k0 + 32 : k0;  // clamped prefetch
    a0 = *(const short8*)(abase + kn);
    a1 = *(const short8*)(abase + kn + 8);
    b0 = *(const short8*)(bbase + kn);
    b1 = *(const short8*)(bbase + kn + 8);
    short8 af[4], bfr[4];
#pragma unroll
    for (int i = 0; i < 4; i++)
      af[i] = *(short8*)&As[wr + i * 16 + (lane & 15)][(lane >> 4) * 8];
#pragma unroll
    for (int j = 0; j < 4; j++)
      bfr[j] = *(short8*)&Bs[wc + j * 16 + (lane & 15)][(lane >> 4) * 8];
#pragma unroll
    for (int i = 0; i < 4; i++)
#pragma unroll
      for (int j = 0; j < 4; j++) acc[i][j] = MFMA(af[i], bfr[j], acc[i][j]);
  }
  const int N = jb.N;
  const float* cin = jb.Cin;
  const int* cri = jb.cinrow;
#pragma unroll
  for (int j = 0; j < 4; j++) {
    int col = n0 + wc + j * 16 + (lane & 15);
    float bv = jb.bias ? to_f(jb.bias[col]) : 0.f;
#pragma unroll
    for (int i = 0; i < 4; i++) {
#pragma unroll
      for (int r = 0; r < 4; r++) {
        int row = m0 + wr + i * 16 + (lane >> 4) * 4 + r;
        float v = acc[i][j][r] + bv;
        if (cin) {
          long long crow = cri ? (long long)cri[row] : (long long)row;
          v += cin[crow * N + col];
        }
        if (jb.flags & 4) v = tanhf(v);
        if (jb.Cf) jb.Cf[(long long)row * N + col] = v;
        if (jb.Ch) jb.Ch[(long long)row * N + col] = __float2bfloat16(v);
      }
    }
  }
}

// ---- encoder fused GEMM + GRU cell (round-2 proven kernel) ----
struct CJob {
  const bf16* A;
  const short* WT;
  const bf16* bias;
  const int* tok;
  const bf16* giTab;  // [vocab][768] gate-major (incl bih)
  float* hF;
  bf16* hBf;
  bf16* out2;  // bse slice
  long long out2s;
  int lda, wst, K, hstride, hoff;
};
struct CJobs {
  CJob j[2];
};

__global__ __launch_bounds__(256) void mj_gemm_cell(CJobs args) {
  CJob jb = args.j[blockIdx.z];
  const int n0 = blockIdx.x * 128, m0 = blockIdx.y * 128;
  __shared__ short As[128][40];
  __shared__ short Bs[128][40];
  __shared__ int toks[128];
  const int tid = threadIdx.x, lane = tid & 63, wave = tid >> 6;
  const int srow = tid >> 1, skoff = (tid & 1) * 16;
  const int wr = (wave >> 1) * 64, wcq = (wave & 1) * 64;

  if (tid < 128) toks[tid] = jb.tok[m0 + tid];
  const short* abase =
      (const short*)jb.A + (long long)(m0 + srow) * jb.lda + skoff;
  const short* bbase = jb.WT + (long long)(n0 + srow) * jb.wst + skoff;

  f32x4 acc[4][4];
#pragma unroll
  for (int i = 0; i < 4; i++)
#pragma unroll
    for (int j = 0; j < 4; j++) acc[i][j] = 0.f;

  short8 a0 = *(const short8*)(abase);
  short8 a1 = *(const short8*)(abase + 8);
  short8 b0 = *(const short8*)(bbase);
  short8 b1 = *(const short8*)(bbase + 8);
  for (int k0 = 0; k0 < jb.K; k0 += 32) {
    __syncthreads();
    *(short8*)&As[srow][skoff] = a0;
    *(short8*)&As[srow][skoff + 8] = a1;
    *(short8*)&Bs[srow][skoff] = b0;
    *(short8*)&Bs[srow][skoff + 8] = b1;
    __syncthreads();
    int kn = (k0 + 32 < jb.K) ? k0 + 32 : k0;
    a0 = *(const short8*)(abase + kn);
    a1 = *(const short8*)(abase + kn + 8);
    b0 = *(const short8*)(bbase + kn);
    b1 = *(const short8*)(bbase + kn + 8);
    short8 af[4], bfr[4];
#pragma unroll
    for (int i = 0; i < 4; i++)
      af[i] = *(short8*)&As[wr + i * 16 + (lane & 15)][(lane >> 4) * 8];
#pragma unroll
    for (int j = 0; j < 4; j++)
      bfr[j] = *(short8*)&Bs[wcq + j * 16 + (lane & 15)][(lane >> 4) * 8];
#pragma unroll
    for (int i = 0; i < 4; i++)
#pragma unroll
      for (int j = 0; j < 4; j++) acc[i][j] = MFMA(af[i], bfr[j], acc[i][j]);
  }

  const int u = lane & 15, hi4 = (lane >> 4) * 4;
  const int i_h = ((n0 + wcq) >> 6) * 16 + u;
  const float b0g = to_f(jb.bias[n0 + wcq + u]);
  const float b1g = to_f(jb.bias[n0 + wcq + 16 + u]);
  const float b2g = to_f(jb.bias[n0 + wcq + 32 + u]);
#pragma unroll
  for (int i = 0; i < 4; i++) {
#pragma unroll
    for (int r = 0; r < 4; r++) {
      int row = m0 + wr + i * 16 + hi4 + r;
      const bf16* gi = jb.giTab + (long long)toks[row - m0] * 768 + i_h;
      float ir = to_f(gi[0]), iz = to_f(gi[256]), in_ = to_f(gi[512]);
      float hr = acc[i][0][r] + b0g;
      float hz = acc[i][1][r] + b1g;
      float hn = acc[i][2][r] + b2g;
      long long hidx = (long long)row * jb.hstride + jb.hoff + i_h;
      float hv = jb.hF[hidx];
      float rr = 1.f / (1.f + expf(-(ir + hr)));
      float zz = 1.f / (1.f + expf(-(iz + hz)));
      float nn = tanhf(in_ + rr * hn);
      float o = (1.f - zz) * nn + zz * hv;
      jb.hF[hidx] = o;
      jb.hBf[hidx] = __float2bfloat16(o);
      jb.out2[(long long)row * jb.out2s + i_h] = __float2bfloat16(o);
    }
  }
}

// ---- attention with in-kernel hWh matvec. One block per batch row. ----
// hw[col] = h[b] . attn_Wh[:,col] (WhT L2-resident); then energies/softmax/
// weighted sum as before. Removes the dependent wc launch.
struct A2Args {
  const bf16* h;     // [2048][256] current hidden (bf16)
  const short* WhT;  // [256][256] attn_Wh^T ([col][k])
  const bf16* proj;  // [2048*24][256] includes attn_b
  const bf16* bse;   // [2048][24*512]
  const void* v;
  const unsigned* dflag;
  bf16* xr;  // xgcAll t slice base, stride 768, writes cols 0:512
};
__global__ __launch_bounds__(256) void attn2_kernel(A2Args a) {
  int b = blockIdx.x, tid = threadIdx.x;
  int wave = tid >> 6, lane = tid & 63;
  __shared__ short hsh[256];
  __shared__ float partial[24][4];
  __shared__ float aw[24];
  const bool isf32 = (*a.dflag != 0u);
  hsh[tid] = ((const short*)a.h)[(long long)b * 256 + tid];
  float vv = ldp(a.v, tid, isf32);
  __syncthreads();
  float hw = 0.f;
  const short* wrow = a.WhT + (size_t)tid * 256;
#pragma unroll 8
  for (int kt = 0; kt < 32; kt++) {
    short8 w8 = *(const short8*)(wrow + kt * 8);
    short8 h8 = *(const short8*)&hsh[kt * 8];
#pragma unroll
    for (int e = 0; e < 8; e++) hw += b2f(h8[e]) * b2f(w8[e]);
  }
  const bf16* pb = a.proj + (long long)b * 24 * 256;
#pragma unroll 4
  for (int s = 0; s < 24; s++) {
    float e = tanhf(hw + to_f(pb[s * 256 + tid]));
    float t = vv * e;
#pragma unroll
    for (int off = 32; off > 0; off >>= 1) t += __shfl_down(t, off, 64);
    if (lane == 0) partial[s][wave] = t;
  }
  __syncthreads();
  if (tid == 0) {
    float sc[24];
    float mx = -1e30f;
    for (int s = 0; s < 24; s++) {
      float xv = partial[s][0] + partial[s][1] + partial[s][2] + partial[s][3];
      sc[s] = xv;
      mx = fmaxf(mx, xv);
    }
    float sum = 0.f;
    for (int s = 0; s < 24; s++) {
      sc[s] = expf(sc[s] - mx);
      sum += sc[s];
    }
    float inv = 1.f / sum;
    for (int s = 0; s < 24; s++) aw[s] = sc[s] * inv;
  }
  __syncthreads();
  const bf16* eb = a.bse + (long long)b * 24 * 512;
  float w0 = 0.f, w1 = 0.f;
#pragma unroll 4
  for (int s = 0; s < 24; s++) {
    float aa = aw[s];
    w0 += aa * to_f(eb[s * 512 + tid]);
    w1 += aa * to_f(eb[s * 512 + 256 + tid]);
  }
  bf16* xb = a.xr + (long long)b * 768;
  xb[tid] = __float2bfloat16(w0);
  xb[256 + tid] = __float2bfloat16(w1);
}

// ---- decoder cell: dual-GEMM (gi_dyn K=512 + gh K=256, separate accs;
// n-gate needs them apart) + fused GRU cell. grid (8,16). ----
struct C2Args {
  const bf16* xr;      // [2048][768] weighted at cols 0:512
  const bf16* hprev;   // [2048][256] bf16
  const short* W7p;    // [1024][512] dec_Wih[300:812]^T perm
  const short* WhhP;   // [1024][256] dec_Whh^T perm
  const bf16* bhhP;    // [1024] dec_bhh perm
  const int* tok;
  const bf16* giTabE;  // [128][768] emb@Wih[0:300]+bih
  float* hF;           // [2048][256] f32, in-place (owner-only access)
  bf16* hnext;         // [2048][256]
  bf16* xout;          // xgcAll t slice base (stride 768), cols 512:768
};

__device__ __forceinline__ void tile_acc3(const short* abase,
                                          const short* bbase, int K,
                                          short (*As)[40], short (*Bs)[40],
                                          int srow, int skoff, int wr,
                                          int wcq, int lane, f32x4 acc[4][3]) {
  short8 a0 = *(const short8*)(abase);
  short8 a1 = *(const short8*)(abase + 8);
  short8 b0 = *(const short8*)(bbase);
  short8 b1 = *(const short8*)(bbase + 8);
  for (int k0 = 0; k0 < K; k0 += 32) {
    __syncthreads();
    *(short8*)&As[srow][skoff] = a0;
    *(short8*)&As[srow][skoff + 8] = a1;
    *(short8*)&Bs[srow][skoff] = b0;
    *(short8*)&Bs[srow][skoff + 8] = b1;
    __syncthreads();
    int kn = (k0 + 32 < K) ? k0 + 32 : k0;  // clamped prefetch
    a0 = *(const short8*)(abase + kn);
    a1 = *(const short8*)(abase + kn + 8);
    b0 = *(const short8*)(bbase + kn);
    b1 = *(const short8*)(bbase + kn + 8);
    short8 af[4], bfr[3];
#pragma unroll
    for (int i = 0; i < 4; i++)
      af[i] = *(short8*)&As[wr + i * 16 + (lane & 15)][(lane >> 4) * 8];
#pragma unroll
    for (int j = 0; j < 3; j++)  // j=3 is gate-pad (zeros), skip
      bfr[j] = *(short8*)&Bs[wcq + j * 16 + (lane & 15)][(lane >> 4) * 8];
#pragma unroll
    for (int i = 0; i < 4; i++)
#pragma unroll
      for (int j = 0; j < 3; j++) acc[i][j] = MFMA(af[i], bfr[j], acc[i][j]);
  }
}

__global__ __launch_bounds__(256) void cell2_kernel(C2Args a) {
  const int n0 = blockIdx.x * 128, m0 = blockIdx.y * 128;
  __shared__ short As[128][40];
  __shared__ short Bs[128][40];
  __shared__ int toks[128];
  const int tid = threadIdx.x, lane = tid & 63, wave = tid >> 6;
  const int srow = tid >> 1, skoff = (tid & 1) * 16;
  const int wr = (wave >> 1) * 64, wcq = (wave & 1) * 64;
  if (tid < 128) toks[tid] = a.tok[m0 + tid];

  f32x4 accA[4][3], accB[4][3];
#pragma unroll
  for (int i = 0; i < 4; i++)
#pragma unroll
    for (int j = 0; j < 3; j++) {
      accA[i][j] = 0.f;
      accB[i][j] = 0.f;
    }
  // phase 1: gi_dyn = weighted @ W7p^T, K=512
  tile_acc3((const short*)a.xr + (long long)(m0 + srow) * 768 + skoff,
            a.W7p + (long long)(n0 + srow) * 512 + skoff, 512, As, Bs, srow,
            skoff, wr, wcq, lane, accA);
  // phase 2: gh = h_prev @ WhhP^T, K=256
  tile_acc3((const short*)a.hprev + (long long)(m0 + srow) * 256 + skoff,
            a.WhhP + (long long)(n0 + srow) * 256 + skoff, 256, As, Bs, srow,
            skoff, wr, wcq, lane, accB);

  const int u = lane & 15, hi4 = (lane >> 4) * 4;
  const int i_h = ((n0 + wcq) >> 6) * 16 + u;
  const float b0g = to_f(a.bhhP[n0 + wcq + u]);
  const float b1g = to_f(a.bhhP[n0 + wcq + 16 + u]);
  const float b2g = to_f(a.bhhP[n0 + wcq + 32 + u]);
#pragma unroll
  for (int i = 0; i < 4; i++) {
#pragma unroll
    for (int r = 0; r < 4; r++) {
      int row = m0 + wr + i * 16 + hi4 + r;
      const bf16* gi = a.giTabE + (long long)toks[row - m0] * 768 + i_h;
      float ir = accA[i][0][r] + to_f(gi[0]);
      float iz = accA[i][1][r] + to_f(gi[256]);
      float in_ = accA[i][2][r] + to_f(gi[512]);
      float hr = accB[i][0][r] + b0g;
      float hz = accB[i][1][r] + b1g;
      float hn = accB[i][2][r] + b2g;
      long long hidx = (long long)row * 256 + i_h;
      float hv = a.hF[hidx];
      float rr = 1.f / (1.f + expf(-(ir + hr)));
      float zz = 1.f / (1.f + expf(-(iz + hz)));
      float nn = tanhf(in_ + rr * hn);
      float o = (1.f - zz) * nn + zz * hv;
      a.hF[hidx] = o;
      a.hnext[hidx] = __float2bfloat16(o);
      a.xout[(long long)row * 768 + 512 + i_h] = __float2bfloat16(o);
    }
  }
}

__global__ void sentinel_kernel(float* out, int n) {
  int i = blockIdx.x * 256 + threadIdx.x;
  if (i < n) out[i] = 123.0f;
}

extern "C" void kernel_launch(void* const* d_in, const int* in_sizes, int n_in,
                              void* d_out, int out_size, void* d_ws,
                              size_t ws_size, hipStream_t stream) {
  const int B = 2048, S = 24, T = 25, VOUT = 128;
  const int* src = (const int*)d_in[0];
  const int* trg = (const int*)d_in[1];
  const void* enc_emb = d_in[2];
  const void* enc_Wih_f = d_in[3];
  const void* enc_Whh_f = d_in[4];
  const void* enc_bih_f = d_in[5];
  const void* enc_bhh_f = d_in[6];
  const void* enc_Wih_b = d_in[7];
  const void* enc_Whh_b = d_in[8];
  const void* enc_bih_b = d_in[9];
  const void* enc_bhh_b = d_in[10];
  const void* enc_fcW = d_in[11];
  const void* enc_fcb = d_in[12];
  const void* attn_Wh = d_in[13];
  const void* attn_We = d_in[14];
  const void* attn_b = d_in[15];
  const void* attn_v = d_in[16];
  const void* dec_emb = d_in[17];
  const void* dec_Wih = d_in[18];
  const void* dec_Whh = d_in[19];
  const void* dec_bih = d_in[20];
  const void* dec_bhh = d_in[21];
  const void* fcW = d_in[22];
  const void* fcb = d_in[23];
  float* out = (float*)d_out;

  // ---- workspace layout ----
  size_t need = 0;
  auto place = [&](size_t bytes) {
    size_t off = need;
    need += (bytes + 255) & ~(size_t)255;
    return off;
  };
  size_t o_flag = place(256);
  size_t o_wstart = need;  // memset-0 region
  size_t oEmbE = place(64 * 320 * 2);
  size_t oEmbD = place(128 * 320 * 2);
  size_t oWT1 = place(768 * 320 * 2);    // enc_Wih_f^T
  size_t oWT2 = place(1024 * 256 * 2);   // enc_Whh_f^T perm
  size_t oWT3 = place(768 * 320 * 2);    // enc_Wih_b^T
  size_t oWT4 = place(1024 * 256 * 2);   // enc_Whh_b^T perm
  size_t oWT5 = place(256 * 512 * 2);    // enc_fcW^T
  size_t oWT6 = place(256 * 512 * 2);    // attn_We^T
  size_t oWhhP = place(1024 * 256 * 2);  // dec_Whh^T perm
  size_t oWhT = place(256 * 256 * 2);    // attn_Wh^T [col][k]
  size_t oW7aT = place(768 * 320 * 2);   // dec_Wih[0:300]^T
  size_t oW7bT = place(1024 * 512 * 2);  // dec_Wih[300:812]^T perm
  size_t oW8aT = place(128 * 320 * 2);   // fcW emb rows^T
  size_t oW8bT = place(128 * 768 * 2);   // fcW k-perm [weighted|hn]
  size_t oB1 = place(768 * 2), oB2 = place(1024 * 2);
  size_t oB3 = place(768 * 2), oB4 = place(1024 * 2);
  size_t oB5 = place(256 * 2), oB6 = place(256 * 2);
  size_t oB7 = place(768 * 2), oBcP = place(1024 * 2), oB8 = place(128 * 2);
  size_t o_wend = need;
  size_t o_bse = place((size_t)B * S * 512 * 2);
  size_t o_proj = place((size_t)B * S * 256 * 2);
  size_t o_xgc = place((size_t)(T - 1) * B * 768 * 2);  // 75.5 MB
  size_t o_hfb = place((size_t)B * 512 * 4);
  size_t o_hb0 = place((size_t)B * 512 * 2);
  size_t o_hb1 = place((size_t)B * 512 * 2);
  size_t o_hd = place((size_t)B * 256 * 4);
  size_t o_hdb0 = place((size_t)B * 256 * 2);
  size_t o_hdb1 = place((size_t)B * 256 * 2);
  size_t o_gtF = place(128 * 768 * 2);
  size_t o_gtB = place(128 * 768 * 2);
  size_t o_gtE = place(128 * 768 * 2);
  size_t o_fcT = place(128 * 128 * 4);

  if (ws_size < need) {
    sentinel_kernel<<<(out_size + 255) / 256, 256, 0, stream>>>(out, out_size);
    return;
  }

  char* base = (char*)d_ws;
  unsigned* dflag = (unsigned*)(base + o_flag);
  bf16* embE = (bf16*)(base + oEmbE);
  bf16* embD = (bf16*)(base + oEmbD);
  short* WT1 = (short*)(base + oWT1);
  short* WT2p = (short*)(base + oWT2);
  short* WT3 = (short*)(base + oWT3);
  short* WT4p = (short*)(base + oWT4);
  short* WT5 = (short*)(base + oWT5);
  short* WT6 = (short*)(base + oWT6);
  short* WhhP = (short*)(base + oWhhP);
  short* WhT = (short*)(base + oWhT);
  short* W7aT = (short*)(base + oW7aT);
  short* W7bTp = (short*)(base + oW7bT);
  short* W8aT = (short*)(base + oW8aT);
  short* W8bT = (short*)(base + oW8bT);
  bf16 *B1 = (bf16*)(base + oB1), *B2p = (bf16*)(base + oB2);
  bf16 *B3 = (bf16*)(base + oB3), *B4p = (bf16*)(base + oB4);
  bf16 *B5 = (bf16*)(base + oB5), *B6 = (bf16*)(base + oB6);
  bf16 *B7 = (bf16*)(base + oB7), *BcP = (bf16*)(base + oBcP);
  bf16* B8 = (bf16*)(base + oB8);
  bf16* bse = (bf16*)(base + o_bse);
  bf16* proj = (bf16*)(base + o_proj);
  bf16* xgcAll = (bf16*)(base + o_xgc);
  float* hfb = (float*)(base + o_hfb);
  bf16* hb[2] = {(bf16*)(base + o_hb0), (bf16*)(base + o_hb1)};
  float* h_d = (float*)(base + o_hd);
  bf16* hdbf[2] = {(bf16*)(base + o_hdb0), (bf16*)(base + o_hdb1)};
  bf16* giTabF = (bf16*)(base + o_gtF);
  bf16* giTabB = (bf16*)(base + o_gtB);
  bf16* giTabE = (bf16*)(base + o_gtE);
  float* fcTab = (float*)(base + o_fcT);

  detect_kernel<<<1, 256, 0, stream>>>(enc_emb, dflag);
  (void)hipMemsetAsync(base + o_wstart, 0, o_wend - o_wstart, stream);

  // ---- weight prep (24 segs exactly) ----
  PrepArgs pa;
  int ns = 0;
  long long tot = 0;
  auto seg = [&](const void* s, long long soff, short* dst, int scols,
                 int dstride, int transp, long long count) {
    pa.src[ns] = s;
    pa.soff[ns] = soff;
    pa.dst[ns] = dst;
    pa.scols[ns] = scols;
    pa.dstride[ns] = dstride;
    pa.transp[ns] = transp;
    pa.prefix[ns] = tot;
    tot += count;
    ns++;
  };
  seg(enc_emb, 0, (short*)embE, 300, 320, 0, 64 * 300);
  seg(dec_emb, 0, (short*)embD, 300, 320, 0, 128 * 300);
  seg(enc_Wih_f, 0, WT1, 768, 320, 1, 230400);
  seg(enc_Whh_f, 0, WT2p, 768, 256, 2, 196608);
  seg(enc_Wih_b, 0, WT3, 768, 320, 1, 230400);
  seg(enc_Whh_b, 0, WT4p, 768, 256, 2, 196608);
  seg(enc_fcW, 0, WT5, 256, 512, 1, 131072);
  seg(attn_We, 0, WT6, 256, 512, 1, 131072);
  seg(dec_Whh, 0, WhhP, 768, 256, 2, 196608);
  seg(attn_Wh, 0, WhT, 256, 256, 1, 65536);
  seg(dec_Wih, 0, W7aT, 768, 320, 1, 300 * 768);                      // 0:300
  seg(dec_Wih, (long long)300 * 768, W7bTp, 768, 512, 2, 512 * 768);  // rest
  seg(fcW, (long long)768 * 128, W8aT, 128, 320, 1, 300 * 128);  // emb
  seg(fcW, (long long)256 * 128, W8bT, 128, 768, 1, 512 * 128);  // weighted
  seg(fcW, 0, W8bT + 512, 128, 768, 1, 256 * 128);               // hn
  seg(enc_bih_f, 0, (short*)B1, 768, 768, 0, 768);
  seg(enc_bhh_f, 0, (short*)B2p, 768, 1024, 3, 768);
  seg(enc_bih_b, 0, (short*)B3, 768, 768, 0, 768);
  seg(enc_bhh_b, 0, (short*)B4p, 768, 1024, 3, 768);
  seg(enc_fcb, 0, (short*)B5, 256, 256, 0, 256);
  seg(attn_b, 0, (short*)B6, 256, 256, 0, 256);
  seg(dec_bih, 0, (short*)B7, 768, 768, 0, 768);
  seg(dec_bhh, 0, (short*)BcP, 768, 1024, 3, 768);
  seg(fcb, 0, (short*)B8, 128, 128, 0, 128);
  pa.prefix[ns] = tot;
  pa.nseg = ns;
  prep_kernel<<<(int)((tot + 255) / 256), 256, 0, stream>>>(pa, dflag);

  (void)hipMemsetAsync(hfb, 0, (size_t)B * 512 * 4, stream);
  (void)hipMemsetAsync(hb[0], 0, (size_t)B * 512 * 2, stream);
  (void)hipMemsetAsync(out, 0, (size_t)B * VOUT * 4, stream);  // outputs[0]=0

  auto launch = [&](const GJob* jobs, int nj, int gx, int gy) {
    GJobs a{};
    for (int i = 0; i < nj; i++) a.j[i] = jobs[i];
    mj_gemm<<<dim3(gx, gy, nj), 256, 0, stream>>>(a);
  };

  // ---- token tables ----
  {
    GJob tj[4];
    tj[0] = {embE, WT1, B1, nullptr, giTabF, nullptr, nullptr,
             320, 320, 320, 128, 768, 0};
    tj[1] = {embE, WT3, B3, nullptr, giTabB, nullptr, nullptr,
             320, 320, 320, 128, 768, 0};
    tj[2] = {embD, W7aT, B7, nullptr, giTabE, nullptr, nullptr,
             320, 320, 320, 128, 768, 0};
    tj[3] = {embD, W8aT, B8, fcTab, nullptr, nullptr, nullptr,
             320, 320, 320, 128, 128, 0};
    launch(tj, 4, 6, 1);
  }

  // ---- encoder: one fused launch per step ----
  for (int s = 0; s < S; s++) {
    CJobs ca{};
    ca.j[0] = {hb[s & 1], WT2p, B2p, src + (size_t)s * B, giTabF,
               hfb, hb[(s + 1) & 1], bse + (size_t)s * 512, 12288,
               512, 256, 256, 512, 0};
    ca.j[1] = {hb[s & 1] + 256, WT4p, B4p, src + (size_t)(S - 1 - s) * B,
               giTabB, hfb, hb[(s + 1) & 1],
               bse + (size_t)(S - 1 - s) * 512 + 256, 12288,
               512, 256, 256, 512, 256};
    mj_gemm_cell<<<dim3(8, 16, 2), 256, 0, stream>>>(ca);
  }

  // ---- mid: hidden (h_d + hdbf0) and proj, one launch ----
  {
    GJob mj[2];
    mj[0] = {hb[0], WT5, B5, h_d, hdbf[0], nullptr, nullptr,
             512, 512, 512, B, 256, 4};
    mj[1] = {bse, WT6, B6, nullptr, proj, nullptr, nullptr,
             512, 512, 512, B * S, 256, 0};
    launch(mj, 2, 2, 384);
  }

  // ---- decoder: 2 launches per step, no wc ----
  for (int t = 0; t < T - 1; t++) {
    bf16* xr = xgcAll + (size_t)t * B * 768;
    A2Args aa{hdbf[t & 1], WhT, proj, bse, attn_v, dflag, xr};
    attn2_kernel<<<B, 256, 0, stream>>>(aa);
    C2Args cc{xr,    hdbf[t & 1], W7bTp, WhhP, BcP,
              trg + (size_t)t * B, giTabE, h_d, hdbf[(t + 1) & 1], xr};
    cell2_kernel<<<dim3(8, 16), 256, 0, stream>>>(cc);
  }

  // ---- logits for all steps, batched ----
  {
    GJob jf = {xgcAll, W8bT, nullptr, out + (size_t)B * VOUT, nullptr,
               fcTab, trg, 768, 768, 768, (T - 1) * B, 128, 0};
    launch(&jf, 1, 1, 384);
  }
}

// Round 10
// 1840.400 us; speedup vs baseline: 4.4105x; 1.4542x over previous
//
#include <hip/hip_runtime.h>
#include <hip/hip_bf16.h>

typedef __hip_bfloat16 bf16;
typedef __attribute__((ext_vector_type(8))) short short8;
typedef __attribute__((ext_vector_type(4))) short short4v;
typedef __attribute__((ext_vector_type(4))) float f32x4;

#define MFMA(va, vb, vc) \
  __builtin_amdgcn_mfma_f32_16x16x32_bf16(va, vb, vc, 0, 0, 0)

__device__ __forceinline__ float to_f(float x) { return x; }
__device__ __forceinline__ float to_f(bf16 x) { return __bfloat162float(x); }
__device__ __forceinline__ float ldp(const void* p, size_t i, bool f32) {
  return f32 ? ((const float*)p)[i] : __bfloat162float(((const bf16*)p)[i]);
}
__device__ __forceinline__ short f2b(float f) {
  bf16 h = __float2bfloat16(f);
  return *reinterpret_cast<short*>(&h);
}
__device__ __forceinline__ float b2f(short s_) {
  unsigned int ui = ((unsigned int)(unsigned short)s_) << 16;
  float f;
  __builtin_memcpy(&f, &ui, 4);
  return f;
}
// gate-interleave permutation: c = g*256+i -> 64*(i>>4) + 16*g + (i&15).
// MFMA n-subtile j == gate in fused cell kernels.
__device__ __forceinline__ int perm1024(int c) {
  return ((c & 255) >> 4) * 64 + (c >> 8) * 16 + (c & 15);
}

// dtype probe: f32 data read as u16 pairs shows implausible bf16 exponents.
__global__ void detect_kernel(const void* __restrict__ probe,
                              unsigned* __restrict__ flag) {
  __shared__ int sbad;
  if (threadIdx.x == 0) sbad = 0;
  __syncthreads();
  const unsigned short* u = (const unsigned short*)probe;
  int bad = 0;
  for (int i = threadIdx.x; i < 2048; i += 256) {
    unsigned short w = u[i];
    unsigned e = (w >> 7) & 0xFFu;
    bool plaus = (w == 0) || (w == 0x8000u) || (e >= 0x60u && e <= 0x7Eu);
    if (!plaus) bad++;
  }
  atomicAdd(&sbad, bad);
  __syncthreads();
  if (threadIdx.x == 0) *flag = (sbad > 100) ? 1u : 0u;
}

// ---- weight prep ----
// transp: 0=copy, 1=transpose, 2=transpose+perm1024, 3=copy+perm1024
#define MAXSEG 24
struct PrepArgs {
  int nseg;
  const void* src[MAXSEG];
  long long soff[MAXSEG];
  short* dst[MAXSEG];
  int scols[MAXSEG];
  int dstride[MAXSEG];
  int transp[MAXSEG];
  long long prefix[MAXSEG + 1];
};
__global__ void prep_kernel(PrepArgs a, const unsigned* __restrict__ dflag) {
  const bool isf32 = (*dflag != 0u);
  long long i = (long long)blockIdx.x * 256 + threadIdx.x;
  if (i >= a.prefix[a.nseg]) return;
  int s = 0;
  while (i >= a.prefix[s + 1]) s++;
  long long loc = i - a.prefix[s];
  long long r = loc / a.scols[s], c = loc % a.scols[s];
  float v = a.src[s] ? ldp(a.src[s], (size_t)(a.soff[s] + loc), isf32) : 0.f;
  int tp = a.transp[s];
  long long idx;
  if (tp == 1)
    idx = c * a.dstride[s] + r;
  else if (tp == 2)
    idx = (long long)perm1024((int)c) * a.dstride[s] + r;
  else if (tp == 3)
    idx = perm1024((int)c);
  else
    idx = r * a.dstride[s] + c;
  a.dst[s][idx] = f2b(v);
}

// ---- multi-job MFMA GEMM, 128x128 tile (tables, mid, hwh, logits) ----
struct GJob {
  const bf16* A;
  const short* WT;
  const bf16* bias;
  float* Cf;
  bf16* Ch;
  const float* Cin;   // optional f32 addend, stride N
  const int* cinrow;  // optional row gather for Cin
  int lda, wst, K, M, N, flags;  // flags: 4=tanh
};
struct GJobs {
  GJob j[4];
};

__global__ __launch_bounds__(256) void mj_gemm(GJobs args) {
  GJob jb = args.j[blockIdx.z];
  const int n0 = blockIdx.x * 128, m0 = blockIdx.y * 128;
  if (n0 >= jb.N || m0 >= jb.M) return;
  __shared__ short As[128][40];
  __shared__ short Bs[128][40];
  const int tid = threadIdx.x, lane = tid & 63, wave = tid >> 6;
  const int srow = tid >> 1, skoff = (tid & 1) * 16;
  const int wr = (wave >> 1) * 64, wc = (wave & 1) * 64;

  const short* abase =
      (const short*)jb.A + (long long)(m0 + srow) * jb.lda + skoff;
  const short* bbase = jb.WT + (long long)(n0 + srow) * jb.wst + skoff;
  f32x4 acc[4][4];
#pragma unroll
  for (int i = 0; i < 4; i++)
#pragma unroll
    for (int j = 0; j < 4; j++) acc[i][j] = 0.f;

  short8 a0 = *(const short8*)(abase);
  short8 a1 = *(const short8*)(abase + 8);
  short8 b0 = *(const short8*)(bbase);
  short8 b1 = *(const short8*)(bbase + 8);
  for (int k0 = 0; k0 < jb.K; k0 += 32) {
    __syncthreads();
    *(short8*)&As[srow][skoff] = a0;
    *(short8*)&As[srow][skoff + 8] = a1;
    *(short8*)&Bs[srow][skoff] = b0;
    *(short8*)&Bs[srow][skoff + 8] = b1;
    __syncthreads();
    int kn = (k0 + 32 < jb.K) ? k0 + 32 : k0;  // clamped prefetch
    a0 = *(const short8*)(abase + kn);
    a1 = *(const short8*)(abase + kn + 8);
    b0 = *(const short8*)(bbase + kn);
    b1 = *(const short8*)(bbase + kn + 8);
    short8 af[4], bfr[4];
#pragma unroll
    for (int i = 0; i < 4; i++)
      af[i] = *(short8*)&As[wr + i * 16 + (lane & 15)][(lane >> 4) * 8];
#pragma unroll
    for (int j = 0; j < 4; j++)
      bfr[j] = *(short8*)&Bs[wc + j * 16 + (lane & 15)][(lane >> 4) * 8];
#pragma unroll
    for (int i = 0; i < 4; i++)
#pragma unroll
      for (int j = 0; j < 4; j++) acc[i][j] = MFMA(af[i], bfr[j], acc[i][j]);
  }
  const int N = jb.N;
  const float* cin = jb.Cin;
  const int* cri = jb.cinrow;
#pragma unroll
  for (int j = 0; j < 4; j++) {
    int col = n0 + wc + j * 16 + (lane & 15);
    float bv = jb.bias ? to_f(jb.bias[col]) : 0.f;
#pragma unroll
    for (int i = 0; i < 4; i++) {
#pragma unroll
      for (int r = 0; r < 4; r++) {
        int row = m0 + wr + i * 16 + (lane >> 4) * 4 + r;
        float v = acc[i][j][r] + bv;
        if (cin) {
          long long crow = cri ? (long long)cri[row] : (long long)row;
          v += cin[crow * N + col];
        }
        if (jb.flags & 4) v = tanhf(v);
        if (jb.Cf) jb.Cf[(long long)row * N + col] = v;
        if (jb.Ch) jb.Ch[(long long)row * N + col] = __float2bfloat16(v);
      }
    }
  }
}

// ---- encoder fused GEMM + GRU cell (round-2 proven kernel) ----
struct CJob {
  const bf16* A;
  const short* WT;
  const bf16* bias;
  const int* tok;
  const bf16* giTab;  // [vocab][768] gate-major (incl bih)
  float* hF;
  bf16* hBf;
  bf16* out2;  // bse slice
  long long out2s;
  int lda, wst, K, hstride, hoff;
};
struct CJobs {
  CJob j[2];
};

__global__ __launch_bounds__(256) void mj_gemm_cell(CJobs args) {
  CJob jb = args.j[blockIdx.z];
  const int n0 = blockIdx.x * 128, m0 = blockIdx.y * 128;
  __shared__ short As[128][40];
  __shared__ short Bs[128][40];
  __shared__ int toks[128];
  const int tid = threadIdx.x, lane = tid & 63, wave = tid >> 6;
  const int srow = tid >> 1, skoff = (tid & 1) * 16;
  const int wr = (wave >> 1) * 64, wcq = (wave & 1) * 64;

  if (tid < 128) toks[tid] = jb.tok[m0 + tid];
  const short* abase =
      (const short*)jb.A + (long long)(m0 + srow) * jb.lda + skoff;
  const short* bbase = jb.WT + (long long)(n0 + srow) * jb.wst + skoff;

  f32x4 acc[4][4];
#pragma unroll
  for (int i = 0; i < 4; i++)
#pragma unroll
    for (int j = 0; j < 4; j++) acc[i][j] = 0.f;

  short8 a0 = *(const short8*)(abase);
  short8 a1 = *(const short8*)(abase + 8);
  short8 b0 = *(const short8*)(bbase);
  short8 b1 = *(const short8*)(bbase + 8);
  for (int k0 = 0; k0 < jb.K; k0 += 32) {
    __syncthreads();
    *(short8*)&As[srow][skoff] = a0;
    *(short8*)&As[srow][skoff + 8] = a1;
    *(short8*)&Bs[srow][skoff] = b0;
    *(short8*)&Bs[srow][skoff + 8] = b1;
    __syncthreads();
    int kn = (k0 + 32 < jb.K) ? k0 + 32 : k0;
    a0 = *(const short8*)(abase + kn);
    a1 = *(const short8*)(abase + kn + 8);
    b0 = *(const short8*)(bbase + kn);
    b1 = *(const short8*)(bbase + kn + 8);
    short8 af[4], bfr[4];
#pragma unroll
    for (int i = 0; i < 4; i++)
      af[i] = *(short8*)&As[wr + i * 16 + (lane & 15)][(lane >> 4) * 8];
#pragma unroll
    for (int j = 0; j < 4; j++)
      bfr[j] = *(short8*)&Bs[wcq + j * 16 + (lane & 15)][(lane >> 4) * 8];
#pragma unroll
    for (int i = 0; i < 4; i++)
#pragma unroll
      for (int j = 0; j < 4; j++) acc[i][j] = MFMA(af[i], bfr[j], acc[i][j]);
  }

  const int u = lane & 15, hi4 = (lane >> 4) * 4;
  const int i_h = ((n0 + wcq) >> 6) * 16 + u;
  const float b0g = to_f(jb.bias[n0 + wcq + u]);
  const float b1g = to_f(jb.bias[n0 + wcq + 16 + u]);
  const float b2g = to_f(jb.bias[n0 + wcq + 32 + u]);
#pragma unroll
  for (int i = 0; i < 4; i++) {
#pragma unroll
    for (int r = 0; r < 4; r++) {
      int row = m0 + wr + i * 16 + hi4 + r;
      const bf16* gi = jb.giTab + (long long)toks[row - m0] * 768 + i_h;
      float ir = to_f(gi[0]), iz = to_f(gi[256]), in_ = to_f(gi[512]);
      float hr = acc[i][0][r] + b0g;
      float hz = acc[i][1][r] + b1g;
      float hn = acc[i][2][r] + b2g;
      long long hidx = (long long)row * jb.hstride + jb.hoff + i_h;
      float hv = jb.hF[hidx];
      float rr = 1.f / (1.f + expf(-(ir + hr)));
      float zz = 1.f / (1.f + expf(-(iz + hz)));
      float nn = tanhf(in_ + rr * hn);
      float o = (1.f - zz) * nn + zz * hv;
      jb.hF[hidx] = o;
      jb.hBf[hidx] = __float2bfloat16(o);
      jb.out2[(long long)row * jb.out2s + i_h] = __float2bfloat16(o);
    }
  }
}

// ---- attention v3: hwh precomputed by mini-GEMM; wide loads, wave-parallel
// softmax. One block per batch row. ----
struct A3Args {
  const bf16* hwh;   // [2048][256] = h @ attn_Wh (bf16)
  const bf16* proj;  // [2048*24][256] includes attn_b
  const bf16* bse;   // [2048][24*512]
  const void* v;
  const unsigned* dflag;
  bf16* xr;  // xgcAll t slice base, stride 768, writes cols 0:512
};
__global__ __launch_bounds__(256) void attn3_kernel(A3Args a) {
  const int b = blockIdx.x, tid = threadIdx.x;
  const int wave = tid >> 6, lane = tid & 63;
  __shared__ float esc[24];
  __shared__ float aw[24];
  const bool isf32 = (*a.dflag != 0u);
  // lane covers 4 contiguous cols: lane*4 .. lane*4+3
  float vv[4], hw[4];
  {
    short4v h4 =
        *(const short4v*)((const short*)a.hwh + (size_t)b * 256 + lane * 4);
#pragma unroll
    for (int e = 0; e < 4; e++) {
      hw[e] = b2f(h4[e]);
      vv[e] = ldp(a.v, lane * 4 + e, isf32);
    }
  }
  // energies: wave w owns s = w*6 .. w*6+5; prefetch all 6 rows
  const short* pb = (const short*)a.proj + (size_t)b * 6144 + lane * 4;
  short4v p4s[6];
#pragma unroll
  for (int i = 0; i < 6; i++)
    p4s[i] = *(const short4v*)(pb + (wave * 6 + i) * 256);
#pragma unroll
  for (int i = 0; i < 6; i++) {
    float t = 0.f;
#pragma unroll
    for (int e = 0; e < 4; e++)
      t += vv[e] * tanhf(hw[e] + b2f(p4s[i][e]));
#pragma unroll
    for (int off = 1; off < 64; off <<= 1) t += __shfl_xor(t, off, 64);
    if (lane == 0) esc[wave * 6 + i] = t;
  }
  __syncthreads();
  if (wave == 0) {
    float xv = (lane < 24) ? esc[lane] : -1e30f;
    float mx = xv;
#pragma unroll
    for (int off = 1; off < 64; off <<= 1)
      mx = fmaxf(mx, __shfl_xor(mx, off, 64));
    float e = (lane < 24) ? expf(xv - mx) : 0.f;
    float sm = e;
#pragma unroll
    for (int off = 1; off < 64; off <<= 1) sm += __shfl_xor(sm, off, 64);
    if (lane < 24) aw[lane] = e / sm;
  }
  __syncthreads();
  // weighted sum: thread owns packed cols 2*tid, 2*tid+1
  const short* eb = (const short*)a.bse + (size_t)b * 12288 + tid * 2;
  float w0 = 0.f, w1 = 0.f;
#pragma unroll
  for (int s = 0; s < 24; s++) {
    unsigned q = *(const unsigned*)(eb + s * 512);
    float aa = aw[s];
    w0 += aa * b2f((short)(q & 0xffff));
    w1 += aa * b2f((short)(q >> 16));
  }
  unsigned o = ((unsigned)(unsigned short)f2b(w1) << 16) |
               (unsigned)(unsigned short)f2b(w0);
  *(unsigned*)((short*)a.xr + (size_t)b * 768 + tid * 2) = o;
}

// ---- decoder cell: dual-GEMM (gi_dyn K=512 + gh K=256, separate accs;
// n-gate needs them apart) + fused GRU cell. grid (8,16). ----
struct C2Args {
  const bf16* xr;      // [2048][768] weighted at cols 0:512
  const bf16* hprev;   // [2048][256] bf16
  const short* W7p;    // [1024][512] dec_Wih[300:812]^T perm
  const short* WhhP;   // [1024][256] dec_Whh^T perm
  const bf16* bhhP;    // [1024] dec_bhh perm
  const int* tok;
  const bf16* giTabE;  // [128][768] emb@Wih[0:300]+bih
  float* hF;           // [2048][256] f32, in-place (owner-only access)
  bf16* hnext;         // [2048][256]
  bf16* xout;          // xgcAll t slice base (stride 768), cols 512:768
};

__device__ __forceinline__ void tile_acc3(const short* abase,
                                          const short* bbase, int K,
                                          short (*As)[40], short (*Bs)[40],
                                          int srow, int skoff, int wr,
                                          int wcq, int lane, f32x4 acc[4][3]) {
  short8 a0 = *(const short8*)(abase);
  short8 a1 = *(const short8*)(abase + 8);
  short8 b0 = *(const short8*)(bbase);
  short8 b1 = *(const short8*)(bbase + 8);
  for (int k0 = 0; k0 < K; k0 += 32) {
    __syncthreads();
    *(short8*)&As[srow][skoff] = a0;
    *(short8*)&As[srow][skoff + 8] = a1;
    *(short8*)&Bs[srow][skoff] = b0;
    *(short8*)&Bs[srow][skoff + 8] = b1;
    __syncthreads();
    int kn = (k0 + 32 < K) ? k0 + 32 : k0;  // clamped prefetch
    a0 = *(const short8*)(abase + kn);
    a1 = *(const short8*)(abase + kn + 8);
    b0 = *(const short8*)(bbase + kn);
    b1 = *(const short8*)(bbase + kn + 8);
    short8 af[4], bfr[3];
#pragma unroll
    for (int i = 0; i < 4; i++)
      af[i] = *(short8*)&As[wr + i * 16 + (lane & 15)][(lane >> 4) * 8];
#pragma unroll
    for (int j = 0; j < 3; j++)  // j=3 is gate-pad (zeros), skip
      bfr[j] = *(short8*)&Bs[wcq + j * 16 + (lane & 15)][(lane >> 4) * 8];
#pragma unroll
    for (int i = 0; i < 4; i++)
#pragma unroll
      for (int j = 0; j < 3; j++) acc[i][j] = MFMA(af[i], bfr[j], acc[i][j]);
  }
}

__global__ __launch_bounds__(256) void cell2_kernel(C2Args a) {
  const int n0 = blockIdx.x * 128, m0 = blockIdx.y * 128;
  __shared__ short As[128][40];
  __shared__ short Bs[128][40];
  __shared__ int toks[128];
  const int tid = threadIdx.x, lane = tid & 63, wave = tid >> 6;
  const int srow = tid >> 1, skoff = (tid & 1) * 16;
  const int wr = (wave >> 1) * 64, wcq = (wave & 1) * 64;
  if (tid < 128) toks[tid] = a.tok[m0 + tid];

  f32x4 accA[4][3], accB[4][3];
#pragma unroll
  for (int i = 0; i < 4; i++)
#pragma unroll
    for (int j = 0; j < 3; j++) {
      accA[i][j] = 0.f;
      accB[i][j] = 0.f;
    }
  // phase 1: gi_dyn = weighted @ W7p^T, K=512
  tile_acc3((const short*)a.xr + (long long)(m0 + srow) * 768 + skoff,
            a.W7p + (long long)(n0 + srow) * 512 + skoff, 512, As, Bs, srow,
            skoff, wr, wcq, lane, accA);
  // phase 2: gh = h_prev @ WhhP^T, K=256
  tile_acc3((const short*)a.hprev + (long long)(m0 + srow) * 256 + skoff,
            a.WhhP + (long long)(n0 + srow) * 256 + skoff, 256, As, Bs, srow,
            skoff, wr, wcq, lane, accB);

  const int u = lane & 15, hi4 = (lane >> 4) * 4;
  const int i_h = ((n0 + wcq) >> 6) * 16 + u;
  const float b0g = to_f(a.bhhP[n0 + wcq + u]);
  const float b1g = to_f(a.bhhP[n0 + wcq + 16 + u]);
  const float b2g = to_f(a.bhhP[n0 + wcq + 32 + u]);
#pragma unroll
  for (int i = 0; i < 4; i++) {
#pragma unroll
    for (int r = 0; r < 4; r++) {
      int row = m0 + wr + i * 16 + hi4 + r;
      const bf16* gi = a.giTabE + (long long)toks[row - m0] * 768 + i_h;
      float ir = accA[i][0][r] + to_f(gi[0]);
      float iz = accA[i][1][r] + to_f(gi[256]);
      float in_ = accA[i][2][r] + to_f(gi[512]);
      float hr = accB[i][0][r] + b0g;
      float hz = accB[i][1][r] + b1g;
      float hn = accB[i][2][r] + b2g;
      long long hidx = (long long)row * 256 + i_h;
      float hv = a.hF[hidx];
      float rr = 1.f / (1.f + expf(-(ir + hr)));
      float zz = 1.f / (1.f + expf(-(iz + hz)));
      float nn = tanhf(in_ + rr * hn);
      float o = (1.f - zz) * nn + zz * hv;
      a.hF[hidx] = o;
      a.hnext[hidx] = __float2bfloat16(o);
      a.xout[(long long)row * 768 + 512 + i_h] = __float2bfloat16(o);
    }
  }
}

__global__ void sentinel_kernel(float* out, int n) {
  int i = blockIdx.x * 256 + threadIdx.x;
  if (i < n) out[i] = 123.0f;
}

extern "C" void kernel_launch(void* const* d_in, const int* in_sizes, int n_in,
                              void* d_out, int out_size, void* d_ws,
                              size_t ws_size, hipStream_t stream) {
  const int B = 2048, S = 24, T = 25, VOUT = 128;
  const int* src = (const int*)d_in[0];
  const int* trg = (const int*)d_in[1];
  const void* enc_emb = d_in[2];
  const void* enc_Wih_f = d_in[3];
  const void* enc_Whh_f = d_in[4];
  const void* enc_bih_f = d_in[5];
  const void* enc_bhh_f = d_in[6];
  const void* enc_Wih_b = d_in[7];
  const void* enc_Whh_b = d_in[8];
  const void* enc_bih_b = d_in[9];
  const void* enc_bhh_b = d_in[10];
  const void* enc_fcW = d_in[11];
  const void* enc_fcb = d_in[12];
  const void* attn_Wh = d_in[13];
  const void* attn_We = d_in[14];
  const void* attn_b = d_in[15];
  const void* attn_v = d_in[16];
  const void* dec_emb = d_in[17];
  const void* dec_Wih = d_in[18];
  const void* dec_Whh = d_in[19];
  const void* dec_bih = d_in[20];
  const void* dec_bhh = d_in[21];
  const void* fcW = d_in[22];
  const void* fcb = d_in[23];
  float* out = (float*)d_out;

  // ---- workspace layout ----
  size_t need = 0;
  auto place = [&](size_t bytes) {
    size_t off = need;
    need += (bytes + 255) & ~(size_t)255;
    return off;
  };
  size_t o_flag = place(256);
  size_t o_wstart = need;  // memset-0 region
  size_t oEmbE = place(64 * 320 * 2);
  size_t oEmbD = place(128 * 320 * 2);
  size_t oWT1 = place(768 * 320 * 2);    // enc_Wih_f^T
  size_t oWT2 = place(1024 * 256 * 2);   // enc_Whh_f^T perm
  size_t oWT3 = place(768 * 320 * 2);    // enc_Wih_b^T
  size_t oWT4 = place(1024 * 256 * 2);   // enc_Whh_b^T perm
  size_t oWT5 = place(256 * 512 * 2);    // enc_fcW^T
  size_t oWT6 = place(256 * 512 * 2);    // attn_We^T
  size_t oWhhP = place(1024 * 256 * 2);  // dec_Whh^T perm
  size_t oWhT = place(256 * 256 * 2);    // attn_Wh^T [col][k]
  size_t oW7aT = place(768 * 320 * 2);   // dec_Wih[0:300]^T
  size_t oW7bT = place(1024 * 512 * 2);  // dec_Wih[300:812]^T perm
  size_t oW8aT = place(128 * 320 * 2);   // fcW emb rows^T
  size_t oW8bT = place(128 * 768 * 2);   // fcW k-perm [weighted|hn]
  size_t oB1 = place(768 * 2), oB2 = place(1024 * 2);
  size_t oB3 = place(768 * 2), oB4 = place(1024 * 2);
  size_t oB5 = place(256 * 2), oB6 = place(256 * 2);
  size_t oB7 = place(768 * 2), oBcP = place(1024 * 2), oB8 = place(128 * 2);
  size_t o_wend = need;
  size_t o_bse = place((size_t)B * S * 512 * 2);
  size_t o_proj = place((size_t)B * S * 256 * 2);
  size_t o_xgc = place((size_t)(T - 1) * B * 768 * 2);  // 75.5 MB
  size_t o_hfb = place((size_t)B * 512 * 4);
  size_t o_hb0 = place((size_t)B * 512 * 2);
  size_t o_hb1 = place((size_t)B * 512 * 2);
  size_t o_hd = place((size_t)B * 256 * 4);
  size_t o_hdb0 = place((size_t)B * 256 * 2);
  size_t o_hdb1 = place((size_t)B * 256 * 2);
  size_t o_hwh = place((size_t)B * 256 * 2);
  size_t o_gtF = place(128 * 768 * 2);
  size_t o_gtB = place(128 * 768 * 2);
  size_t o_gtE = place(128 * 768 * 2);
  size_t o_fcT = place(128 * 128 * 4);

  if (ws_size < need) {
    sentinel_kernel<<<(out_size + 255) / 256, 256, 0, stream>>>(out, out_size);
    return;
  }

  char* base = (char*)d_ws;
  unsigned* dflag = (unsigned*)(base + o_flag);
  bf16* embE = (bf16*)(base + oEmbE);
  bf16* embD = (bf16*)(base + oEmbD);
  short* WT1 = (short*)(base + oWT1);
  short* WT2p = (short*)(base + oWT2);
  short* WT3 = (short*)(base + oWT3);
  short* WT4p = (short*)(base + oWT4);
  short* WT5 = (short*)(base + oWT5);
  short* WT6 = (short*)(base + oWT6);
  short* WhhP = (short*)(base + oWhhP);
  short* WhT = (short*)(base + oWhT);
  short* W7aT = (short*)(base + oW7aT);
  short* W7bTp = (short*)(base + oW7bT);
  short* W8aT = (short*)(base + oW8aT);
  short* W8bT = (short*)(base + oW8bT);
  bf16 *B1 = (bf16*)(base + oB1), *B2p = (bf16*)(base + oB2);
  bf16 *B3 = (bf16*)(base + oB3), *B4p = (bf16*)(base + oB4);
  bf16 *B5 = (bf16*)(base + oB5), *B6 = (bf16*)(base + oB6);
  bf16 *B7 = (bf16*)(base + oB7), *BcP = (bf16*)(base + oBcP);
  bf16* B8 = (bf16*)(base + oB8);
  bf16* bse = (bf16*)(base + o_bse);
  bf16* proj = (bf16*)(base + o_proj);
  bf16* xgcAll = (bf16*)(base + o_xgc);
  float* hfb = (float*)(base + o_hfb);
  bf16* hb[2] = {(bf16*)(base + o_hb0), (bf16*)(base + o_hb1)};
  float* h_d = (float*)(base + o_hd);
  bf16* hdbf[2] = {(bf16*)(base + o_hdb0), (bf16*)(base + o_hdb1)};
  bf16* hwh = (bf16*)(base + o_hwh);
  bf16* giTabF = (bf16*)(base + o_gtF);
  bf16* giTabB = (bf16*)(base + o_gtB);
  bf16* giTabE = (bf16*)(base + o_gtE);
  float* fcTab = (float*)(base + o_fcT);

  detect_kernel<<<1, 256, 0, stream>>>(enc_emb, dflag);
  (void)hipMemsetAsync(base + o_wstart, 0, o_wend - o_wstart, stream);

  // ---- weight prep (24 segs exactly) ----
  PrepArgs pa;
  int ns = 0;
  long long tot = 0;
  auto seg = [&](const void* s, long long soff, short* dst, int scols,
                 int dstride, int transp, long long count) {
    pa.src[ns] = s;
    pa.soff[ns] = soff;
    pa.dst[ns] = dst;
    pa.scols[ns] = scols;
    pa.dstride[ns] = dstride;
    pa.transp[ns] = transp;
    pa.prefix[ns] = tot;
    tot += count;
    ns++;
  };
  seg(enc_emb, 0, (short*)embE, 300, 320, 0, 64 * 300);
  seg(dec_emb, 0, (short*)embD, 300, 320, 0, 128 * 300);
  seg(enc_Wih_f, 0, WT1, 768, 320, 1, 230400);
  seg(enc_Whh_f, 0, WT2p, 768, 256, 2, 196608);
  seg(enc_Wih_b, 0, WT3, 768, 320, 1, 230400);
  seg(enc_Whh_b, 0, WT4p, 768, 256, 2, 196608);
  seg(enc_fcW, 0, WT5, 256, 512, 1, 131072);
  seg(attn_We, 0, WT6, 256, 512, 1, 131072);
  seg(dec_Whh, 0, WhhP, 768, 256, 2, 196608);
  seg(attn_Wh, 0, WhT, 256, 256, 1, 65536);
  seg(dec_Wih, 0, W7aT, 768, 320, 1, 300 * 768);                      // 0:300
  seg(dec_Wih, (long long)300 * 768, W7bTp, 768, 512, 2, 512 * 768);  // rest
  seg(fcW, (long long)768 * 128, W8aT, 128, 320, 1, 300 * 128);  // emb
  seg(fcW, (long long)256 * 128, W8bT, 128, 768, 1, 512 * 128);  // weighted
  seg(fcW, 0, W8bT + 512, 128, 768, 1, 256 * 128);               // hn
  seg(enc_bih_f, 0, (short*)B1, 768, 768, 0, 768);
  seg(enc_bhh_f, 0, (short*)B2p, 768, 1024, 3, 768);
  seg(enc_bih_b, 0, (short*)B3, 768, 768, 0, 768);
  seg(enc_bhh_b, 0, (short*)B4p, 768, 1024, 3, 768);
  seg(enc_fcb, 0, (short*)B5, 256, 256, 0, 256);
  seg(attn_b, 0, (short*)B6, 256, 256, 0, 256);
  seg(dec_bih, 0, (short*)B7, 768, 768, 0, 768);
  seg(dec_bhh, 0, (short*)BcP, 768, 1024, 3, 768);
  seg(fcb, 0, (short*)B8, 128, 128, 0, 128);
  pa.prefix[ns] = tot;
  pa.nseg = ns;
  prep_kernel<<<(int)((tot + 255) / 256), 256, 0, stream>>>(pa, dflag);

  (void)hipMemsetAsync(hfb, 0, (size_t)B * 512 * 4, stream);
  (void)hipMemsetAsync(hb[0], 0, (size_t)B * 512 * 2, stream);
  (void)hipMemsetAsync(out, 0, (size_t)B * VOUT * 4, stream);  // outputs[0]=0

  auto launch = [&](const GJob* jobs, int nj, int gx, int gy) {
    GJobs a{};
    for (int i = 0; i < nj; i++) a.j[i] = jobs[i];
    mj_gemm<<<dim3(gx, gy, nj), 256, 0, stream>>>(a);
  };

  // ---- token tables ----
  {
    GJob tj[4];
    tj[0] = {embE, WT1, B1, nullptr, giTabF, nullptr, nullptr,
             320, 320, 320, 128, 768, 0};
    tj[1] = {embE, WT3, B3, nullptr, giTabB, nullptr, nullptr,
             320, 320, 320, 128, 768, 0};
    tj[2] = {embD, W7aT, B7, nullptr, giTabE, nullptr, nullptr,
             320, 320, 320, 128, 768, 0};
    tj[3] = {embD, W8aT, B8, fcTab, nullptr, nullptr, nullptr,
             320, 320, 320, 128, 128, 0};
    launch(tj, 4, 6, 1);
  }

  // ---- encoder: one fused launch per step ----
  for (int s = 0; s < S; s++) {
    CJobs ca{};
    ca.j[0] = {hb[s & 1], WT2p, B2p, src + (size_t)s * B, giTabF,
               hfb, hb[(s + 1) & 1], bse + (size_t)s * 512, 12288,
               512, 256, 256, 512, 0};
    ca.j[1] = {hb[s & 1] + 256, WT4p, B4p, src + (size_t)(S - 1 - s) * B,
               giTabB, hfb, hb[(s + 1) & 1],
               bse + (size_t)(S - 1 - s) * 512 + 256, 12288,
               512, 256, 256, 512, 256};
    mj_gemm_cell<<<dim3(8, 16, 2), 256, 0, stream>>>(ca);
  }

  // ---- mid: hidden (h_d + hdbf0) and proj, one launch ----
  {
    GJob mj[2];
    mj[0] = {hb[0], WT5, B5, h_d, hdbf[0], nullptr, nullptr,
             512, 512, 512, B, 256, 4};
    mj[1] = {bse, WT6, B6, nullptr, proj, nullptr, nullptr,
             512, 512, 512, B * S, 256, 0};
    launch(mj, 2, 2, 384);
  }

  // ---- decoder: 3 launches per step (hwh mini-GEMM, attn3, cell2) ----
  for (int t = 0; t < T - 1; t++) {
    bf16* xr = xgcAll + (size_t)t * B * 768;
    GJob jh = {hdbf[t & 1], WhT, nullptr, nullptr, hwh, nullptr, nullptr,
               256, 256, 256, B, 256, 0};
    launch(&jh, 1, 2, 16);
    A3Args aa{hwh, proj, bse, attn_v, dflag, xr};
    attn3_kernel<<<B, 256, 0, stream>>>(aa);
    C2Args cc{xr,    hdbf[t & 1], W7bTp, WhhP, BcP,
              trg + (size_t)t * B, giTabE, h_d, hdbf[(t + 1) & 1], xr};
    cell2_kernel<<<dim3(8, 16), 256, 0, stream>>>(cc);
  }

  // ---- logits for all steps, batched ----
  {
    GJob jf = {xgcAll, W8bT, nullptr, out + (size_t)B * VOUT, nullptr,
               fcTab, trg, 768, 768, 768, (T - 1) * B, 128, 0};
    launch(&jf, 1, 1, 384);
  }
}